// Round 6
// baseline (1075.851 us; speedup 1.0000x reference)
//
#include <hip/hip_runtime.h>
#include <hip/hip_fp8.h>

#define B_ 2
#define H_ 224
#define W_ 224
#define HW_ 50176
#define E_ 768
#define M_ 196

typedef __attribute__((ext_vector_type(8))) short short8;
typedef __attribute__((ext_vector_type(4))) float floatx4;

__device__ __forceinline__ float bf2f(ushort u){ return __uint_as_float(((unsigned)u)<<16); }
__device__ __forceinline__ ushort f2bf(float f){
  unsigned b = __float_as_uint(f);
  b += 0x7fffu + ((b>>16)&1u);
  return (ushort)(b>>16);
}
// HW fp8 (OCP e4m3 on gfx950): pack 4 relu'd floats -> 4 fp8 bytes in one uint
__device__ __forceinline__ unsigned pack4_fp8(float a, float b, float c, float d){
  int v = __builtin_amdgcn_cvt_pk_fp8_f32(a, b, 0, false);   // bits [15:0]
  v = __builtin_amdgcn_cvt_pk_fp8_f32(c, d, v, true);        // bits [31:16]
  return (unsigned)v;
}

// ---------------- merged prep + edge kernel (independent work, one dispatch):
// blocks 0..47:  fold BN2 into conv2 weights -> wt2[plane][co][8] (coalesced)
// block  48:     fold BN1 -> A[64 co][32 k]
// blocks 49..440: edge conv + gradient_map + similarity + per-seg stats
__global__ void prep_edge_k(const float* __restrict__ w2, const float* __restrict__ cb2,
                            const float* __restrict__ g2, const float* __restrict__ be2,
                            const float* __restrict__ mn2, const float* __restrict__ vr2,
                            ushort* __restrict__ wt2, float* __restrict__ bias2,
                            const float* __restrict__ w1, const float* __restrict__ cb1,
                            const float* __restrict__ g1, const float* __restrict__ be1,
                            const float* __restrict__ mn1, const float* __restrict__ vr1,
                            ushort* __restrict__ wA, float* __restrict__ bias1,
                            const float* __restrict__ img, const int* __restrict__ seg,
                            const float* __restrict__ ew, float* __restrict__ out,
                            float* __restrict__ counts, float* __restrict__ sims,
                            int* __restrict__ scnt){
  __shared__ ushort WT[9216];     // 16 co x 576 (co-major, src order)
  __shared__ float aux[196];      // invs[16] for prep2 | cnt for edge
  __shared__ float aux2[196];     // ssum for edge
  int tid = threadIdx.x;
  if (blockIdx.x < 48){
    int co0 = blockIdx.x * 16;
    if (tid < 16){
      float inv = g2[co0+tid] * rsqrtf(vr2[co0+tid] + 1e-5f);
      aux[tid] = inv;
      bias2[co0+tid] = cb2[co0+tid]*inv + be2[co0+tid] - mn2[co0+tid]*inv;
    }
    __syncthreads();
    #pragma unroll
    for (int j = 0; j < 36; j++){
      int idx = j*256 + tid;                 // 0..9215 = col*576 + (ci*9+tap)
      WT[idx] = f2bf(w2[(size_t)co0*576 + idx] * aux[idx/576]);
    }
    __syncthreads();
    #pragma unroll
    for (int j = 0; j < 5; j++){
      int o = j*256 + tid;                   // 0..1151
      if (o < 1152){
        int tapkc = o >> 4, col = o & 15;
        int tap = tapkc >> 3, kc = tapkc & 7;
        ushort tmp[8];
        #pragma unroll
        for (int e=0; e<8; e++)
          tmp[e] = WT[col*576 + (kc*8+e)*9 + tap];
        *reinterpret_cast<uint4*>(&wt2[(size_t)((tap*8 + kc)*768 + co0 + col)*8]) =
            *reinterpret_cast<const uint4*>(tmp);
      }
    }
    return;
  }
  if (blockIdx.x == 48){
    #pragma unroll
    for (int j = 0; j < 8; j++){
      int t = j*256 + tid;                   // 2048 exactly
      int co = t >> 5, k = t & 31;
      float inv = g1[co] * rsqrtf(vr1[co] + 1e-5f);
      float val = 0.f;
      if (k < 27){
        int tap = k / 3, ci = k % 3;
        val = w1[co*27 + ci*9 + tap] * inv;
      }
      wA[co*32 + k] = f2bf(val);
      if (k == 0) bias1[co] = cb1[co]*inv + be1[co] - mn1[co]*inv;
    }
    return;
  }
  // ---- edge path
  if (tid < 196){ aux[tid]=0.f; aux2[tid]=0.f; }
  __syncthreads();
  int p = (blockIdx.x-49)*256 + tid;
  int b = p / HW_; int r = p % HW_; int h = r / W_; int w = r % W_;
  float e0=0.f, e1=0.f;
  #pragma unroll
  for (int ky=0;ky<3;ky++){
    int hh=h+ky-1;
    #pragma unroll
    for (int kx=0;kx<3;kx++){
      int ww=w+kx-1;
      float gv=0.f;
      if (hh>=0&&hh<H_&&ww>=0&&ww<W_){
        int base = b*3*HW_ + hh*W_ + ww;
        gv=(img[base]+img[base+HW_]+img[base+2*HW_])*(1.f/3.f);
      }
      e0 += gv*ew[ky*3+kx];
      e1 += gv*ew[9+ky*3+kx];
    }
  }
  float gm = sqrtf(e0*e0+e1*e1+1e-8f);
  out[301056 + p] = gm;
  int sg = seg[p];
  out[401408 + p] = (float)sg;
  float sim = fminf(fmaxf(1.f-gm,0.f),1.f);
  atomicAdd(&aux[sg], 1.f);
  atomicAdd(&aux2[sg], sim);
  __syncthreads();
  if (tid < 196){
    int gid = b*196 + tid;
    float c = aux[tid];
    atomicAdd(&counts[gid], c);
    atomicAdd(&sims[gid], aux2[tid]);
    atomicAdd(&scnt[b*196+tid], (int)c);
  }
}

// ---------------- conv1 + BN1 + ReLU via bf16 MFMA (blocks 2..393);
// blocks 0..1: per-batch exclusive scan of segment counts (independent)
__launch_bounds__(256)
__global__ void conv1_scan_k(const float* __restrict__ img, const ushort* __restrict__ wA,
                             const float* __restrict__ bias1, ushort* __restrict__ xbf,
                             const int* __restrict__ scnt, int* __restrict__ offs,
                             int* __restrict__ curs){
  __shared__ float HL[3*18*20];          // fp32 halo, row pad 20 (also scan's a[])
  __shared__ ushort IC[256*40];          // im2col [px][32k pad40]
  __shared__ ushort AW[64*40];           // weights [co][32k pad40]
  __shared__ float b1s[64];
  int tid = threadIdx.x;
  if (blockIdx.x < 2){
    // ---- scan path
    int* a = reinterpret_cast<int*>(HL);
    int s = blockIdx.x;
    a[tid] = (tid<196)? scnt[s*196+tid] : 0;
    __syncthreads();
    for (int d=1; d<256; d<<=1){
      int v = a[tid];
      int u = (tid>=d)? a[tid-d] : 0;
      __syncthreads();
      a[tid] = v+u;
      __syncthreads();
    }
    if (tid<=196) offs[s*200+tid] = tid ? a[tid-1] : 0;
    if (tid<196)  curs[s*196+tid] = tid ? a[tid-1] : 0;
    return;
  }
  int bid = blockIdx.x - 2;
  int b = bid / 196, tile = bid % 196;
  int tr = tile / 14, tc = tile % 14;
  int h0 = tr*16, w0 = tc*16;
  for (int idx = tid; idx < 972; idx += 256){
    int ci = idx / 324, rem = idx % 324;
    int r = rem / 18, c = rem % 18;
    int hh = h0 + r - 1, ww = w0 + c - 1;
    float v = (hh>=0 && hh<H_ && ww>=0 && ww<W_) ? img[((b*3+ci)*H_+hh)*W_+ww] : 0.f;
    HL[ci*360 + r*20 + c] = v;
  }
  {
    int row = tid >> 2, cp = (tid&3)*8;
    uint4 v = *reinterpret_cast<const uint4*>(&wA[row*32 + cp]);
    *reinterpret_cast<uint4*>(&AW[row*40 + cp]) = v;
  }
  if (tid < 64) b1s[tid] = bias1[tid];
  __syncthreads();
  {
    int pr = tid >> 4, pc = tid & 15;
    ushort tmp[32];
    #pragma unroll
    for (int ky=0; ky<3; ky++)
      #pragma unroll
      for (int kx=0; kx<3; kx++)
        #pragma unroll
        for (int ci=0; ci<3; ci++)
          tmp[(ky*3+kx)*3+ci] = f2bf(HL[ci*360 + (pr+ky)*20 + (pc+kx)]);
    #pragma unroll
    for (int k=27; k<32; k++) tmp[k] = 0;
    #pragma unroll
    for (int j=0; j<4; j++)
      *reinterpret_cast<uint4*>(&IC[tid*40 + j*8]) = *reinterpret_cast<const uint4*>(&tmp[j*8]);
  }
  __syncthreads();
  int lane = tid & 63, wave = tid >> 6;
  int q = lane >> 4, l15 = lane & 15;
  short8 af[4], bfr[4];
  #pragma unroll
  for (int f=0; f<4; f++)
    af[f] = *reinterpret_cast<const short8*>(&AW[(f*16+l15)*40 + q*8]);
  #pragma unroll
  for (int f=0; f<4; f++)
    bfr[f] = *reinterpret_cast<const short8*>(&IC[(wave*64+f*16+l15)*40 + q*8]);
  floatx4 acc[4][4];
  #pragma unroll
  for (int fc=0; fc<4; fc++)
    #pragma unroll
    for (int fp=0; fp<4; fp++){
      floatx4 z = (floatx4){0.f,0.f,0.f,0.f};
      acc[fc][fp] = __builtin_amdgcn_mfma_f32_16x16x32_bf16(af[fc], bfr[fp], z, 0,0,0);
    }
  #pragma unroll
  for (int fp=0; fp<4; fp++){
    int pxl = wave*64 + fp*16 + l15;
    size_t gp = (size_t)b*HW_ + (size_t)(h0 + (pxl>>4))*W_ + (w0 + (pxl&15));
    #pragma unroll
    for (int fc=0; fc<4; fc++){
      int co4 = fc*16 + q*4;
      ushort o[4];
      #pragma unroll
      for (int r=0; r<4; r++) o[r] = f2bf(fmaxf(acc[fc][fp][r] + b1s[co4+r], 0.f));
      *reinterpret_cast<uint2*>(&xbf[gp*64 + co4]) = *reinterpret_cast<const uint2*>(o);
    }
  }
}

// ---------------- conv2 (dilated 3x3, 64->768) + BN2 + ReLU via bf16 MFMA implicit GEMM
// v10: barrier-free loop (v9) + BOTH operands register-double-buffered (true m201
// phase pattern): per iteration {issue bx(hs+1) 8x ds_read + af(hs+1) 4x global} ->
// sched_barrier(0) -> {32 MFMA on [cur]}. Cluster consumes data issued a full
// iteration earlier; compiler emits counted lgkmcnt(8)/vmcnt(4) waits (12 newer
// loads stay in flight) -> per-step load stall -> 0. v8 lesson: the fence is what
// stops the compiler from sinking the prefetch (v9 kept af[2]: VGPR 92+32=124).
// VGPR check: ~190 means bx[2] kept; ~124 means collapsed. 3 blocks/CU (LDS
// 3x51.2KB=153.6 <= 160KB, regs ~320x3 <= 2048/SIMD) for +50% TLP.
// grid (392, 7): y==0 runs the scatter stage; y>=1 is conv2 with co0=(y-1)*128.
__launch_bounds__(256, 3)
__global__ void conv2_scatter_k(const ushort* __restrict__ xbf, const ushort* __restrict__ wt2,
                                const float* __restrict__ bias2, unsigned char* __restrict__ feats,
                                const int* __restrict__ seg, int* __restrict__ curs,
                                int* __restrict__ list){
  // XH: 8 planes x 400 px x 16B = 51200 B (write-once halo; epilogue reuses as EP)
  __shared__ ushort SM[25600];
  ushort* XH = SM;
  int tid = threadIdx.x;
  if (blockIdx.y == 0){
    // ---- scatter path: global pixel indices into per-(batch,segment) lists
    if (blockIdx.x < 392){
      int p = blockIdx.x*256 + tid;
      int b = p / HW_;
      int pos = atomicAdd(&curs[b*196+seg[p]], 1);
      list[b*HW_ + pos] = p;
    }
    return;
  }
  int lane = tid & 63, wave = tid >> 6;
  int wc = wave >> 1, wp = wave & 1;       // wc: co-half (64), wp: px-half (8 rows)
  int q = lane >> 4, l15 = lane & 15;
  int bt = blockIdx.x / 196, tile = blockIdx.x % 196;
  int tr = tile / 14, tc = tile % 14;
  int co0 = (blockIdx.y - 1) * 128;
  int h0 = tr*16, w0 = tc*16;

  // ---- stage X halo once: 400 px (20x20), thread=px reads full 128B pixel row
  for (int px = tid; px < 400; px += 256){
    int hr = px / 20, wcol = px % 20;
    int hh = h0 + hr - 2, ww = w0 + wcol - 2;
    bool ok = (hh>=0 && hh<H_ && ww>=0 && ww<W_);
    const uint4* src = reinterpret_cast<const uint4*>(&xbf[(((size_t)bt*H_+hh)*W_+ww)*64]);
    #pragma unroll
    for (int chl=0; chl<8; chl++){
      uint4 val = ok ? src[chl] : make_uint4(0u,0u,0u,0u);
      *reinterpret_cast<uint4*>(&XH[chl*3200 + px*8]) = val;
    }
  }
  __syncthreads();   // XH ready; ONLY barrier before the epilogue

  floatx4 acc[4][8];
  #pragma unroll
  for (int i=0;i<4;i++)
    #pragma unroll
    for (int j=0;j<8;j++) acc[i][j] = (floatx4){0.f,0.f,0.f,0.f};

  // per-lane invariant bases
  const int xb = q*3200 + wp*1280 + l15*8;   // X: + half*12800 + (dyr*20+dxr)*8 + fp*160
  // W global base: plane = hs*4 + q; af[f](hs) = wt2[((hs*4+q)*768 + co0 + wc*64 + f*16 + l15)*8]
  const ushort* wgl = wt2 + ((size_t)q*768 + (size_t)(co0 + wc*64 + l15))*8;

  short8 af[2][4], bx[2][8];
  #pragma unroll
  for (int f=0; f<4; f++)
    af[0][f] = *reinterpret_cast<const short8*>(&wgl[f*128]);
  #pragma unroll
  for (int fp=0; fp<8; fp++)
    bx[0][fp] = *reinterpret_cast<const short8*>(&XH[xb + fp*160]);  // xoff(0)=0

  #pragma unroll
  for (int hs = 0; hs < 18; hs++){
    const int cur = hs & 1, nxt = cur ^ 1;
    if (hs < 17){                                    // issue step hs+1 operand loads
      const int nh = hs + 1;
      const int ntap = nh >> 1, nhalf = nh & 1;
      const int ndyr = (ntap/3)*2, ndxr = (ntap%3)*2;
      const int nxoff = nhalf*12800 + ndyr*160 + ndxr*8;   // compile-time (unrolled)
      #pragma unroll
      for (int fp=0; fp<8; fp++)
        bx[nxt][fp] = *reinterpret_cast<const short8*>(&XH[xb + nxoff + fp*160]);
      #pragma unroll
      for (int f=0; f<4; f++)
        af[nxt][f] = *reinterpret_cast<const short8*>(&wgl[(size_t)nh*24576 + f*128]);
    }
    __builtin_amdgcn_sched_barrier(0);               // loads stay above this cluster
    __builtin_amdgcn_s_setprio(1);
    #pragma unroll
    for (int fc=0; fc<4; fc++)
      #pragma unroll
      for (int fp=0; fp<8; fp++)
        acc[fc][fp] = __builtin_amdgcn_mfma_f32_16x16x32_bf16(af[cur][fc], bx[cur][fp],
                                                              acc[fc][fp], 0,0,0);
    __builtin_amdgcn_s_setprio(0);
  }

  // ---- epilogue: bias+relu, HW fp8 pack -> LDS transpose -> coalesced stores.
  // XH dead; reuse SM as EP[256 px][34 uint] (pad 34: both sides max 2-way = free).
  __syncthreads();
  unsigned* EP = reinterpret_cast<unsigned*>(SM);    // 256*34*4 = 34,816 B <= 51,200 B
  #pragma unroll
  for (int fc=0; fc<4; fc++){
    float4 bs = *reinterpret_cast<const float4*>(&bias2[co0 + wc*64 + fc*16 + q*4]);
    int cslot = wc*16 + fc*4 + q;                    // uint slot = co_local/4 (0..31)
    #pragma unroll
    for (int fp=0; fp<8; fp++){
      int p_local = (wp*8 + fp)*16 + l15;            // 0..255
      EP[p_local*34 + cslot] = pack4_fp8(
          fmaxf(acc[fc][fp][0] + bs.x, 0.f), fmaxf(acc[fc][fp][1] + bs.y, 0.f),
          fmaxf(acc[fc][fp][2] + bs.z, 0.f), fmaxf(acc[fc][fp][3] + bs.w, 0.f));
    }
  }
  __syncthreads();
  {
    // 32 consecutive lanes cover one pixel's 128 contiguous bytes -> 4 cache
    // lines per store instruction (vs 64 with a 4B/lane stride-768 scatter).
    size_t gbase = ((size_t)bt*HW_ + (size_t)(tr*16)*W_ + tc*16)*768 + co0;
    int c = tid & 31, t5 = tid >> 5;
    #pragma unroll
    for (int j=0; j<32; j++){
      int px = j*8 + t5;                             // 0..255, each exactly once
      int rr = px >> 4, wcol = px & 15;
      *reinterpret_cast<unsigned*>(
        &feats[gbase + ((size_t)rr*W_ + wcol)*768 + c*4]) = EP[px*34 + c];
    }
  }
}

// ---------------- gather pooling: full-image lists, 8-way split, fp8 feats (4B/lane)
__global__ void pool_k(const unsigned char* __restrict__ feats, const int* __restrict__ list,
                       const int* __restrict__ offs, float* __restrict__ meansum,
                       float* __restrict__ maxv){
  int m = blockIdx.x, qu = blockIdx.y, b = blockIdx.z, tid = threadIdx.x;
  int base = offs[b*200+m], end = offs[b*200+m+1];
  int len = end - base;
  int b0 = base + ((len*qu) >> 3);
  int b1 = base + ((len*(qu+1)) >> 3);
  const int* lp = &list[b*HW_];
  int co4 = tid*4;
  float s0=0.f,s1=0.f,s2=0.f,s3=0.f;
  float m0=0.f,m1=0.f,m2=0.f,m3=0.f;
  int i = b0;
  // HW fp8->f32 (v_cvt_f32_fp8 byte-select)
  #define ACC(v) { \
    float f0=__builtin_amdgcn_cvt_f32_fp8((int)(v),0), f1=__builtin_amdgcn_cvt_f32_fp8((int)(v),1); \
    float f2=__builtin_amdgcn_cvt_f32_fp8((int)(v),2), f3=__builtin_amdgcn_cvt_f32_fp8((int)(v),3); \
    s0+=f0; s1+=f1; s2+=f2; s3+=f3; \
    m0=fmaxf(m0,f0); m1=fmaxf(m1,f1); m2=fmaxf(m2,f2); m3=fmaxf(m3,f3); }
  for (; i+3 < b1; i += 4){
    unsigned va = *reinterpret_cast<const unsigned*>(&feats[(size_t)lp[i  ]*768 + co4]);
    unsigned vb = *reinterpret_cast<const unsigned*>(&feats[(size_t)lp[i+1]*768 + co4]);
    unsigned vc = *reinterpret_cast<const unsigned*>(&feats[(size_t)lp[i+2]*768 + co4]);
    unsigned vd = *reinterpret_cast<const unsigned*>(&feats[(size_t)lp[i+3]*768 + co4]);
    ACC(va) ACC(vb) ACC(vc) ACC(vd)
  }
  for (; i < b1; i++){
    unsigned v = *reinterpret_cast<const unsigned*>(&feats[(size_t)lp[i]*768 + co4]);
    ACC(v)
  }
  #undef ACC
  int gs = b*196 + m;
  float* ms = &meansum[(size_t)gs*768 + co4];
  unsigned* mv = reinterpret_cast<unsigned*>(&maxv[(size_t)gs*768 + co4]);
  atomicAdd(&ms[0], s0); atomicAdd(&ms[1], s1);
  atomicAdd(&ms[2], s2); atomicAdd(&ms[3], s3);
  atomicMax(&mv[0], __float_as_uint(m0)); atomicMax(&mv[1], __float_as_uint(m1));
  atomicMax(&mv[2], __float_as_uint(m2)); atomicMax(&mv[3], __float_as_uint(m3));
}

// ---------------- fusion GEMM via bf16 MFMA, K-split; concat built inline from
// meansum/maxv/counts during A staging
__launch_bounds__(256)
__global__ void fusion_mfma_k(const float* __restrict__ meansum, const float* __restrict__ maxv,
                              const float* __restrict__ counts, const float* __restrict__ fw,
                              float* __restrict__ partial){
  __shared__ ushort SM2[2*128*72];      // AL (concat rows) | BL (fw rows)
  ushort* AL = SM2;
  ushort* BL = SM2 + 128*72;
  int tid = threadIdx.x;
  int lane = tid & 63, wave = tid >> 6;
  int wc = wave >> 1, wp = wave & 1;       // wc: m-half, wp: co-half
  int q = lane >> 4, l15 = lane & 15;
  int co0 = blockIdx.x * 128;
  int m0  = blockIdx.y * 128;
  int ksz = blockIdx.z;
  floatx4 acc[4][4];
  for (int i=0;i<4;i++) for (int j=0;j<4;j++) acc[i][j] = (floatx4){0.f,0.f,0.f,0.f};

  for (int kb=0; kb<3; kb++){
    int k0 = ksz*192 + kb*64;
    __syncthreads();
    #pragma unroll
    for (int i=0;i<4;i++){
      int idx = tid + 256*i;                 // 0..1023
      int row = idx >> 3, c8 = (idx & 7) * 8;
      int gm = m0 + row;
      float4 a0 = make_float4(0.f,0.f,0.f,0.f), a1 = a0;
      if (gm < 392){
        int k = k0 + c8;                     // chunk never straddles 768 boundary
        if (k < 768){
          float invc = 1.f / fmaxf(counts[gm], 1.f);
          a0 = *reinterpret_cast<const float4*>(&meansum[gm*768 + k]);
          a1 = *reinterpret_cast<const float4*>(&meansum[gm*768 + k + 4]);
          a0.x*=invc; a0.y*=invc; a0.z*=invc; a0.w*=invc;
          a1.x*=invc; a1.y*=invc; a1.z*=invc; a1.w*=invc;
        } else {
          a0 = *reinterpret_cast<const float4*>(&maxv[gm*768 + k - 768]);
          a1 = *reinterpret_cast<const float4*>(&maxv[gm*768 + k - 768 + 4]);
        }
      }
      ushort ua[8] = { f2bf(a0.x),f2bf(a0.y),f2bf(a0.z),f2bf(a0.w),
                       f2bf(a1.x),f2bf(a1.y),f2bf(a1.z),f2bf(a1.w) };
      *reinterpret_cast<uint4*>(&AL[row*72 + c8]) = *reinterpret_cast<uint4*>(ua);
      float4 b0 = *reinterpret_cast<const float4*>(&fw[(co0+row)*1536 + k0 + c8]);
      float4 b1 = *reinterpret_cast<const float4*>(&fw[(co0+row)*1536 + k0 + c8 + 4]);
      ushort ub[8] = { f2bf(b0.x),f2bf(b0.y),f2bf(b0.z),f2bf(b0.w),
                       f2bf(b1.x),f2bf(b1.y),f2bf(b1.z),f2bf(b1.w) };
      *reinterpret_cast<uint4*>(&BL[row*72 + c8]) = *reinterpret_cast<uint4*>(ub);
    }
    __syncthreads();
    #pragma unroll
    for (int ks=0; ks<64; ks+=32){
      short8 af[4], bfr[4];
      #pragma unroll
      for (int f=0; f<4; f++)
        af[f] = *reinterpret_cast<const short8*>(&AL[(wc*64+f*16+l15)*72 + ks + q*8]);
      #pragma unroll
      for (int f=0; f<4; f++)
        bfr[f] = *reinterpret_cast<const short8*>(&BL[(wp*64+f*16+l15)*72 + ks + q*8]);
      #pragma unroll
      for (int fm=0; fm<4; fm++)
        #pragma unroll
        for (int fn=0; fn<4; fn++)
          acc[fm][fn] = __builtin_amdgcn_mfma_f32_16x16x32_bf16(af[fm], bfr[fn], acc[fm][fn], 0,0,0);
    }
  }
  float* pp = &partial[(size_t)ksz * 301056];
  #pragma unroll
  for (int fm=0; fm<4; fm++){
    #pragma unroll
    for (int r2=0; r2<4; r2++){
      int m = m0 + wc*64 + fm*16 + q*4 + r2;
      if (m >= 392) continue;
      #pragma unroll
      for (int fn=0; fn<4; fn++){
        int co = co0 + wp*64 + fn*16 + l15;
        pp[(size_t)m*768 + co] = acc[fm][fn][r2];
      }
    }
  }
}

// ---------------- fusion epilogue: sum 8 K-split partials, bias, W_k scale, positional add
__global__ void fuse_ep_k(const float* __restrict__ partial, const float* __restrict__ fb,
                          const float* __restrict__ sims, const float* __restrict__ counts,
                          const float* __restrict__ cent, const float* __restrict__ pw,
                          const float* __restrict__ pb, float* __restrict__ out){
  int t = blockIdx.x*256 + threadIdx.x;    // 392*768 exactly
  int gm = t / 768, co = t % 768;
  float s = 0.f;
  #pragma unroll
  for (int k=0;k<8;k++) s += partial[(size_t)k*301056 + t];
  float wk = sims[gm] / fmaxf(counts[gm], 1.f);
  float cx = cent[gm*2 + 0] * (1.f/224.f);
  float cy = cent[gm*2 + 1] * (1.f/224.f);
  out[t] = (s + fb[co]) * wk + cx*pw[co*2] + cy*pw[co*2+1] + pb[co];
}

extern "C" void kernel_launch(void* const* d_in, const int* in_sizes, int n_in,
                              void* d_out, int out_size, void* d_ws, size_t ws_size,
                              hipStream_t stream){
  const float* img  = (const float*)d_in[0];
  const int*   seg  = (const int*)  d_in[1];
  const float* cent = (const float*)d_in[2];
  const float* c1w  = (const float*)d_in[3];
  const float* c1b  = (const float*)d_in[4];
  const float* bn1g = (const float*)d_in[5];
  const float* bn1b = (const float*)d_in[6];
  const float* bn1m = (const float*)d_in[7];
  const float* bn1v = (const float*)d_in[8];
  const float* c2w  = (const float*)d_in[9];
  const float* c2b  = (const float*)d_in[10];
  const float* bn2g = (const float*)d_in[11];
  const float* bn2b = (const float*)d_in[12];
  const float* bn2m = (const float*)d_in[13];
  const float* bn2v = (const float*)d_in[14];
  const float* ew   = (const float*)d_in[15];
  const float* pw   = (const float*)d_in[16];
  const float* pb   = (const float*)d_in[17];
  const float* fwp  = (const float*)d_in[18];
  const float* fbp  = (const float*)d_in[19];
  float* out = (float*)d_out;
  char* ws = (char*)d_ws;

  ushort* xbf    = (ushort*)(ws + 0);          //  12,845,056
  ushort* wt2    = (ushort*)(ws + 12845056);   //     884,736
  float*  bias2  = (float*) (ws + 13729792);   //       3,072
  float*  meansum= (float*) (ws + 13732864);   //   1,204,224  (memset region start)
  float*  maxv   = (float*) (ws + 14937088);   //   1,204,224
  float*  counts = (float*) (ws + 16141312);   //       1,568
  float*  sims   = (float*) (ws + 16142880);   //       1,568
  int*    scnt   = (int*)   (ws + 16144448);   //       3,136  (memset region end)
  int*    offs   = (int*)   (ws + 16147584);   //       3,200
  int*    curs   = (int*)   (ws + 16150784);   //       3,136
  int*    list   = (int*)   (ws + 16154112);   //     401,408  (global px indices)
  ushort* wA     = (ushort*)(ws + 16154112);   //       4,096 (aliases list; dead after conv1)
  float*  bias1  = (float*) (ws + 16158208);   //         256 (aliases list; dead after conv1)
  unsigned char* feats = (unsigned char*)(ws + 16555520);  // 77,070,336 (fp8 e4m3)
  float*  partial= (float*) (ws + 16555520);   //   9,633,792 (aliases feats; used after pooling)

  (void)hipMemsetAsync(ws + 13732864, 0, 2414720, stream);
  prep_edge_k<<<441, 256, 0, stream>>>(c2w, c2b, bn2g, bn2b, bn2m, bn2v, wt2, bias2,
                                       c1w, c1b, bn1g, bn1b, bn1m, bn1v, wA, bias1,
                                       img, seg, ew, out, counts, sims, scnt);
  conv1_scan_k<<<394, 256, 0, stream>>>(img, wA, bias1, xbf, scnt, offs, curs);
  conv2_scatter_k<<<dim3(392, 7), 256, 0, stream>>>(xbf, wt2, bias2, feats, seg, curs, list);
  pool_k<<<dim3(196, 8, 2), 192, 0, stream>>>(feats, list, offs, meansum, maxv);
  fusion_mfma_k<<<dim3(6, 4, 8), 256, 0, stream>>>(meansum, maxv, counts, fwp, partial);
  fuse_ep_k<<<1176, 256, 0, stream>>>(partial, fbp, sims, counts, cent, pw, pb, out);
}

// Round 7
// 303.858 us; speedup vs baseline: 3.5406x; 3.5406x over previous
//
#include <hip/hip_runtime.h>
#include <hip/hip_fp8.h>

#define B_ 2
#define H_ 224
#define W_ 224
#define HW_ 50176
#define E_ 768
#define M_ 196

typedef __attribute__((ext_vector_type(8))) short short8;
typedef __attribute__((ext_vector_type(4))) float floatx4;

__device__ __forceinline__ float bf2f(ushort u){ return __uint_as_float(((unsigned)u)<<16); }
__device__ __forceinline__ ushort f2bf(float f){
  unsigned b = __float_as_uint(f);
  b += 0x7fffu + ((b>>16)&1u);
  return (ushort)(b>>16);
}
// HW fp8 (OCP e4m3 on gfx950): pack 4 relu'd floats -> 4 fp8 bytes in one uint
__device__ __forceinline__ unsigned pack4_fp8(float a, float b, float c, float d){
  int v = __builtin_amdgcn_cvt_pk_fp8_f32(a, b, 0, false);   // bits [15:0]
  v = __builtin_amdgcn_cvt_pk_fp8_f32(c, d, v, true);        // bits [31:16]
  return (unsigned)v;
}

// ---------------- merged prep + edge kernel (independent work, one dispatch):
// blocks 0..47:  fold BN2 into conv2 weights -> wt2[plane][co][8] (coalesced)
// block  48:     fold BN1 -> A[64 co][32 k]
// blocks 49..440: edge conv + gradient_map + similarity + per-seg stats
__global__ void prep_edge_k(const float* __restrict__ w2, const float* __restrict__ cb2,
                            const float* __restrict__ g2, const float* __restrict__ be2,
                            const float* __restrict__ mn2, const float* __restrict__ vr2,
                            ushort* __restrict__ wt2, float* __restrict__ bias2,
                            const float* __restrict__ w1, const float* __restrict__ cb1,
                            const float* __restrict__ g1, const float* __restrict__ be1,
                            const float* __restrict__ mn1, const float* __restrict__ vr1,
                            ushort* __restrict__ wA, float* __restrict__ bias1,
                            const float* __restrict__ img, const int* __restrict__ seg,
                            const float* __restrict__ ew, float* __restrict__ out,
                            float* __restrict__ counts, float* __restrict__ sims,
                            int* __restrict__ scnt){
  __shared__ ushort WT[9216];     // 16 co x 576 (co-major, src order)
  __shared__ float aux[196];      // invs[16] for prep2 | cnt for edge
  __shared__ float aux2[196];     // ssum for edge
  int tid = threadIdx.x;
  if (blockIdx.x < 48){
    int co0 = blockIdx.x * 16;
    if (tid < 16){
      float inv = g2[co0+tid] * rsqrtf(vr2[co0+tid] + 1e-5f);
      aux[tid] = inv;
      bias2[co0+tid] = cb2[co0+tid]*inv + be2[co0+tid] - mn2[co0+tid]*inv;
    }
    __syncthreads();
    #pragma unroll
    for (int j = 0; j < 36; j++){
      int idx = j*256 + tid;                 // 0..9215 = col*576 + (ci*9+tap)
      WT[idx] = f2bf(w2[(size_t)co0*576 + idx] * aux[idx/576]);
    }
    __syncthreads();
    #pragma unroll
    for (int j = 0; j < 5; j++){
      int o = j*256 + tid;                   // 0..1151
      if (o < 1152){
        int tapkc = o >> 4, col = o & 15;
        int tap = tapkc >> 3, kc = tapkc & 7;
        ushort tmp[8];
        #pragma unroll
        for (int e=0; e<8; e++)
          tmp[e] = WT[col*576 + (kc*8+e)*9 + tap];
        *reinterpret_cast<uint4*>(&wt2[(size_t)((tap*8 + kc)*768 + co0 + col)*8]) =
            *reinterpret_cast<const uint4*>(tmp);
      }
    }
    return;
  }
  if (blockIdx.x == 48){
    #pragma unroll
    for (int j = 0; j < 8; j++){
      int t = j*256 + tid;                   // 2048 exactly
      int co = t >> 5, k = t & 31;
      float inv = g1[co] * rsqrtf(vr1[co] + 1e-5f);
      float val = 0.f;
      if (k < 27){
        int tap = k / 3, ci = k % 3;
        val = w1[co*27 + ci*9 + tap] * inv;
      }
      wA[co*32 + k] = f2bf(val);
      if (k == 0) bias1[co] = cb1[co]*inv + be1[co] - mn1[co]*inv;
    }
    return;
  }
  // ---- edge path
  if (tid < 196){ aux[tid]=0.f; aux2[tid]=0.f; }
  __syncthreads();
  int p = (blockIdx.x-49)*256 + tid;
  int b = p / HW_; int r = p % HW_; int h = r / W_; int w = r % W_;
  float e0=0.f, e1=0.f;
  #pragma unroll
  for (int ky=0;ky<3;ky++){
    int hh=h+ky-1;
    #pragma unroll
    for (int kx=0;kx<3;kx++){
      int ww=w+kx-1;
      float gv=0.f;
      if (hh>=0&&hh<H_&&ww>=0&&ww<W_){
        int base = b*3*HW_ + hh*W_ + ww;
        gv=(img[base]+img[base+HW_]+img[base+2*HW_])*(1.f/3.f);
      }
      e0 += gv*ew[ky*3+kx];
      e1 += gv*ew[9+ky*3+kx];
    }
  }
  float gm = sqrtf(e0*e0+e1*e1+1e-8f);
  out[301056 + p] = gm;
  int sg = seg[p];
  out[401408 + p] = (float)sg;
  float sim = fminf(fmaxf(1.f-gm,0.f),1.f);
  atomicAdd(&aux[sg], 1.f);
  atomicAdd(&aux2[sg], sim);
  __syncthreads();
  if (tid < 196){
    int gid = b*196 + tid;
    float c = aux[tid];
    atomicAdd(&counts[gid], c);
    atomicAdd(&sims[gid], aux2[tid]);
    atomicAdd(&scnt[b*196+tid], (int)c);
  }
}

// ---------------- conv1 + BN1 + ReLU via bf16 MFMA (blocks 2..393);
// blocks 0..1: per-batch exclusive scan of segment counts (independent)
__launch_bounds__(256)
__global__ void conv1_scan_k(const float* __restrict__ img, const ushort* __restrict__ wA,
                             const float* __restrict__ bias1, ushort* __restrict__ xbf,
                             const int* __restrict__ scnt, int* __restrict__ offs,
                             int* __restrict__ curs){
  __shared__ float HL[3*18*20];          // fp32 halo, row pad 20 (also scan's a[])
  __shared__ ushort IC[256*40];          // im2col [px][32k pad40]
  __shared__ ushort AW[64*40];           // weights [co][32k pad40]
  __shared__ float b1s[64];
  int tid = threadIdx.x;
  if (blockIdx.x < 2){
    // ---- scan path
    int* a = reinterpret_cast<int*>(HL);
    int s = blockIdx.x;
    a[tid] = (tid<196)? scnt[s*196+tid] : 0;
    __syncthreads();
    for (int d=1; d<256; d<<=1){
      int v = a[tid];
      int u = (tid>=d)? a[tid-d] : 0;
      __syncthreads();
      a[tid] = v+u;
      __syncthreads();
    }
    if (tid<=196) offs[s*200+tid] = tid ? a[tid-1] : 0;
    if (tid<196)  curs[s*196+tid] = tid ? a[tid-1] : 0;
    return;
  }
  int bid = blockIdx.x - 2;
  int b = bid / 196, tile = bid % 196;
  int tr = tile / 14, tc = tile % 14;
  int h0 = tr*16, w0 = tc*16;
  for (int idx = tid; idx < 972; idx += 256){
    int ci = idx / 324, rem = idx % 324;
    int r = rem / 18, c = rem % 18;
    int hh = h0 + r - 1, ww = w0 + c - 1;
    float v = (hh>=0 && hh<H_ && ww>=0 && ww<W_) ? img[((b*3+ci)*H_+hh)*W_+ww] : 0.f;
    HL[ci*360 + r*20 + c] = v;
  }
  {
    int row = tid >> 2, cp = (tid&3)*8;
    uint4 v = *reinterpret_cast<const uint4*>(&wA[row*32 + cp]);
    *reinterpret_cast<uint4*>(&AW[row*40 + cp]) = v;
  }
  if (tid < 64) b1s[tid] = bias1[tid];
  __syncthreads();
  {
    int pr = tid >> 4, pc = tid & 15;
    ushort tmp[32];
    #pragma unroll
    for (int ky=0; ky<3; ky++)
      #pragma unroll
      for (int kx=0; kx<3; kx++)
        #pragma unroll
        for (int ci=0; ci<3; ci++)
          tmp[(ky*3+kx)*3+ci] = f2bf(HL[ci*360 + (pr+ky)*20 + (pc+kx)]);
    #pragma unroll
    for (int k=27; k<32; k++) tmp[k] = 0;
    #pragma unroll
    for (int j=0; j<4; j++)
      *reinterpret_cast<uint4*>(&IC[tid*40 + j*8]) = *reinterpret_cast<const uint4*>(&tmp[j*8]);
  }
  __syncthreads();
  int lane = tid & 63, wave = tid >> 6;
  int q = lane >> 4, l15 = lane & 15;
  short8 af[4], bfr[4];
  #pragma unroll
  for (int f=0; f<4; f++)
    af[f] = *reinterpret_cast<const short8*>(&AW[(f*16+l15)*40 + q*8]);
  #pragma unroll
  for (int f=0; f<4; f++)
    bfr[f] = *reinterpret_cast<const short8*>(&IC[(wave*64+f*16+l15)*40 + q*8]);
  floatx4 acc[4][4];
  #pragma unroll
  for (int fc=0; fc<4; fc++)
    #pragma unroll
    for (int fp=0; fp<4; fp++){
      floatx4 z = (floatx4){0.f,0.f,0.f,0.f};
      acc[fc][fp] = __builtin_amdgcn_mfma_f32_16x16x32_bf16(af[fc], bfr[fp], z, 0,0,0);
    }
  #pragma unroll
  for (int fp=0; fp<4; fp++){
    int pxl = wave*64 + fp*16 + l15;
    size_t gp = (size_t)b*HW_ + (size_t)(h0 + (pxl>>4))*W_ + (w0 + (pxl&15));
    #pragma unroll
    for (int fc=0; fc<4; fc++){
      int co4 = fc*16 + q*4;
      ushort o[4];
      #pragma unroll
      for (int r=0; r<4; r++) o[r] = f2bf(fmaxf(acc[fc][fp][r] + b1s[co4+r], 0.f));
      *reinterpret_cast<uint2*>(&xbf[gp*64 + co4]) = *reinterpret_cast<const uint2*>(o);
    }
  }
}

// ---------------- conv2 (dilated 3x3, 64->768) + BN2 + ReLU via bf16 MFMA implicit GEMM
// v11: barrier-free loop + HALF-CLUSTER software pipeline within the measured register
// budget. Budget law (v10 post-mortem): per-SIMD VGPR pool = 512 -> at 2 waves/SIMD
// each wave gets 256 unified regs; acc[4][8]=128 AGPR leaves arch <= 128. Full double
// buffering of bx (64) + af (32) doesn't fit (v10 spilled acc: VGPR 84, 4 GB scratch
// traffic). v11 splits bx into A(fp0-3)/B(fp4-7): per step
//   {issue af(hs+1) + bxB(hs)} -> fence -> 16 MFMA on bxA
//   {issue bxA(hs+1)}          -> fence -> 16 MFMA on bxB
// Every ds_read has a full 16-MFMA cluster between issue and use (compiler emits
// counted lgkmcnt(4)); frag regs = 32+16+16 = 64 -> arch ~115, no spill.
// grid (392, 7): y==0 runs the scatter stage; y>=1 is conv2 with co0=(y-1)*128.
__launch_bounds__(256, 2)
__global__ void conv2_scatter_k(const ushort* __restrict__ xbf, const ushort* __restrict__ wt2,
                                const float* __restrict__ bias2, unsigned char* __restrict__ feats,
                                const int* __restrict__ seg, int* __restrict__ curs,
                                int* __restrict__ list){
  // XH: 8 planes x 400 px x 16B = 51200 B (write-once halo; epilogue reuses as EP)
  __shared__ ushort SM[25600];
  ushort* XH = SM;
  int tid = threadIdx.x;
  if (blockIdx.y == 0){
    // ---- scatter path: global pixel indices into per-(batch,segment) lists
    if (blockIdx.x < 392){
      int p = blockIdx.x*256 + tid;
      int b = p / HW_;
      int pos = atomicAdd(&curs[b*196+seg[p]], 1);
      list[b*HW_ + pos] = p;
    }
    return;
  }
  int lane = tid & 63, wave = tid >> 6;
  int wc = wave >> 1, wp = wave & 1;       // wc: co-half (64), wp: px-half (8 rows)
  int q = lane >> 4, l15 = lane & 15;
  int bt = blockIdx.x / 196, tile = blockIdx.x % 196;
  int tr = tile / 14, tc = tile % 14;
  int co0 = (blockIdx.y - 1) * 128;
  int h0 = tr*16, w0 = tc*16;

  // ---- stage X halo once: 400 px (20x20), thread=px reads full 128B pixel row
  for (int px = tid; px < 400; px += 256){
    int hr = px / 20, wcol = px % 20;
    int hh = h0 + hr - 2, ww = w0 + wcol - 2;
    bool ok = (hh>=0 && hh<H_ && ww>=0 && ww<W_);
    const uint4* src = reinterpret_cast<const uint4*>(&xbf[(((size_t)bt*H_+hh)*W_+ww)*64]);
    #pragma unroll
    for (int chl=0; chl<8; chl++){
      uint4 val = ok ? src[chl] : make_uint4(0u,0u,0u,0u);
      *reinterpret_cast<uint4*>(&XH[chl*3200 + px*8]) = val;
    }
  }
  __syncthreads();   // XH ready; ONLY barrier before the epilogue

  floatx4 acc[4][8];
  #pragma unroll
  for (int i=0;i<4;i++)
    #pragma unroll
    for (int j=0;j<8;j++) acc[i][j] = (floatx4){0.f,0.f,0.f,0.f};

  // per-lane invariant bases
  const int xb = q*3200 + wp*1280 + l15*8;   // X: + half*12800 + (dyr*20+dxr)*8 + fp*160
  // W global base: plane = hs*4 + q; af[f](hs) = wt2[((hs*4+q)*768 + co0 + wc*64 + f*16 + l15)*8]
  const ushort* wgl = wt2 + ((size_t)q*768 + (size_t)(co0 + wc*64 + l15))*8;

  short8 af[2][4], bxA[4], bxB[4];
  #pragma unroll
  for (int f=0; f<4; f++)
    af[0][f] = *reinterpret_cast<const short8*>(&wgl[f*128]);
  #pragma unroll
  for (int fp=0; fp<4; fp++)
    bxA[fp] = *reinterpret_cast<const short8*>(&XH[xb + fp*160]);    // xoff(0)=0

  #pragma unroll
  for (int hs = 0; hs < 18; hs++){
    const int cur = hs & 1, nxt = cur ^ 1;
    const int tap = hs >> 1, half = hs & 1;
    const int dyr = (tap/3)*2, dxr = (tap%3)*2;
    const int xoff = half*12800 + dyr*160 + dxr*8;       // compile-time (unrolled)
    // ---- phase A issue: af(hs+1) [global, ~2 clusters of cover] + bxB(hs)
    if (hs < 17){
      #pragma unroll
      for (int f=0; f<4; f++)
        af[nxt][f] = *reinterpret_cast<const short8*>(&wgl[(size_t)(hs+1)*24576 + f*128]);
    }
    #pragma unroll
    for (int fp=0; fp<4; fp++)
      bxB[fp] = *reinterpret_cast<const short8*>(&XH[xb + xoff + (4+fp)*160]);
    __builtin_amdgcn_sched_barrier(0);
    __builtin_amdgcn_s_setprio(1);
    #pragma unroll
    for (int fc=0; fc<4; fc++)
      #pragma unroll
      for (int fp=0; fp<4; fp++)
        acc[fc][fp] = __builtin_amdgcn_mfma_f32_16x16x32_bf16(af[cur][fc], bxA[fp],
                                                              acc[fc][fp], 0,0,0);
    __builtin_amdgcn_s_setprio(0);
    // ---- phase B issue: bxA(hs+1) (WAR vs cluster A is in program order -> safe)
    if (hs < 17){
      const int nh = hs + 1;
      const int ntap = nh >> 1, nhalf = nh & 1;
      const int nxoff = nhalf*12800 + ((ntap/3)*2)*160 + ((ntap%3)*2)*8;
      #pragma unroll
      for (int fp=0; fp<4; fp++)
        bxA[fp] = *reinterpret_cast<const short8*>(&XH[xb + nxoff + fp*160]);
    }
    __builtin_amdgcn_sched_barrier(0);
    __builtin_amdgcn_s_setprio(1);
    #pragma unroll
    for (int fc=0; fc<4; fc++)
      #pragma unroll
      for (int fp=0; fp<4; fp++)
        acc[fc][4+fp] = __builtin_amdgcn_mfma_f32_16x16x32_bf16(af[cur][fc], bxB[fp],
                                                                acc[fc][4+fp], 0,0,0);
    __builtin_amdgcn_s_setprio(0);
  }

  // ---- epilogue: bias+relu, HW fp8 pack -> LDS transpose -> coalesced stores.
  // XH dead; reuse SM as EP[256 px][34 uint] (pad 34: both sides max 2-way = free).
  __syncthreads();
  unsigned* EP = reinterpret_cast<unsigned*>(SM);    // 256*34*4 = 34,816 B <= 51,200 B
  #pragma unroll
  for (int fc=0; fc<4; fc++){
    float4 bs = *reinterpret_cast<const float4*>(&bias2[co0 + wc*64 + fc*16 + q*4]);
    int cslot = wc*16 + fc*4 + q;                    // uint slot = co_local/4 (0..31)
    #pragma unroll
    for (int fp=0; fp<8; fp++){
      int p_local = (wp*8 + fp)*16 + l15;            // 0..255
      EP[p_local*34 + cslot] = pack4_fp8(
          fmaxf(acc[fc][fp][0] + bs.x, 0.f), fmaxf(acc[fc][fp][1] + bs.y, 0.f),
          fmaxf(acc[fc][fp][2] + bs.z, 0.f), fmaxf(acc[fc][fp][3] + bs.w, 0.f));
    }
  }
  __syncthreads();
  {
    // 32 consecutive lanes cover one pixel's 128 contiguous bytes -> 4 cache
    // lines per store instruction (vs 64 with a 4B/lane stride-768 scatter).
    size_t gbase = ((size_t)bt*HW_ + (size_t)(tr*16)*W_ + tc*16)*768 + co0;
    int c = tid & 31, t5 = tid >> 5;
    #pragma unroll
    for (int j=0; j<32; j++){
      int px = j*8 + t5;                             // 0..255, each exactly once
      int rr = px >> 4, wcol = px & 15;
      *reinterpret_cast<unsigned*>(
        &feats[gbase + ((size_t)rr*W_ + wcol)*768 + c*4]) = EP[px*34 + c];
    }
  }
}

// ---------------- gather pooling: full-image lists, 8-way split, fp8 feats (4B/lane)
__global__ void pool_k(const unsigned char* __restrict__ feats, const int* __restrict__ list,
                       const int* __restrict__ offs, float* __restrict__ meansum,
                       float* __restrict__ maxv){
  int m = blockIdx.x, qu = blockIdx.y, b = blockIdx.z, tid = threadIdx.x;
  int base = offs[b*200+m], end = offs[b*200+m+1];
  int len = end - base;
  int b0 = base + ((len*qu) >> 3);
  int b1 = base + ((len*(qu+1)) >> 3);
  const int* lp = &list[b*HW_];
  int co4 = tid*4;
  float s0=0.f,s1=0.f,s2=0.f,s3=0.f;
  float m0=0.f,m1=0.f,m2=0.f,m3=0.f;
  int i = b0;
  // HW fp8->f32 (v_cvt_f32_fp8 byte-select)
  #define ACC(v) { \
    float f0=__builtin_amdgcn_cvt_f32_fp8((int)(v),0), f1=__builtin_amdgcn_cvt_f32_fp8((int)(v),1); \
    float f2=__builtin_amdgcn_cvt_f32_fp8((int)(v),2), f3=__builtin_amdgcn_cvt_f32_fp8((int)(v),3); \
    s0+=f0; s1+=f1; s2+=f2; s3+=f3; \
    m0=fmaxf(m0,f0); m1=fmaxf(m1,f1); m2=fmaxf(m2,f2); m3=fmaxf(m3,f3); }
  for (; i+3 < b1; i += 4){
    unsigned va = *reinterpret_cast<const unsigned*>(&feats[(size_t)lp[i  ]*768 + co4]);
    unsigned vb = *reinterpret_cast<const unsigned*>(&feats[(size_t)lp[i+1]*768 + co4]);
    unsigned vc = *reinterpret_cast<const unsigned*>(&feats[(size_t)lp[i+2]*768 + co4]);
    unsigned vd = *reinterpret_cast<const unsigned*>(&feats[(size_t)lp[i+3]*768 + co4]);
    ACC(va) ACC(vb) ACC(vc) ACC(vd)
  }
  for (; i < b1; i++){
    unsigned v = *reinterpret_cast<const unsigned*>(&feats[(size_t)lp[i]*768 + co4]);
    ACC(v)
  }
  #undef ACC
  int gs = b*196 + m;
  float* ms = &meansum[(size_t)gs*768 + co4];
  unsigned* mv = reinterpret_cast<unsigned*>(&maxv[(size_t)gs*768 + co4]);
  atomicAdd(&ms[0], s0); atomicAdd(&ms[1], s1);
  atomicAdd(&ms[2], s2); atomicAdd(&ms[3], s3);
  atomicMax(&mv[0], __float_as_uint(m0)); atomicMax(&mv[1], __float_as_uint(m1));
  atomicMax(&mv[2], __float_as_uint(m2)); atomicMax(&mv[3], __float_as_uint(m3));
}

// ---------------- fusion GEMM via bf16 MFMA, K-split; concat built inline from
// meansum/maxv/counts during A staging
__launch_bounds__(256)
__global__ void fusion_mfma_k(const float* __restrict__ meansum, const float* __restrict__ maxv,
                              const float* __restrict__ counts, const float* __restrict__ fw,
                              float* __restrict__ partial){
  __shared__ ushort SM2[2*128*72];      // AL (concat rows) | BL (fw rows)
  ushort* AL = SM2;
  ushort* BL = SM2 + 128*72;
  int tid = threadIdx.x;
  int lane = tid & 63, wave = tid >> 6;
  int wc = wave >> 1, wp = wave & 1;       // wc: m-half, wp: co-half
  int q = lane >> 4, l15 = lane & 15;
  int co0 = blockIdx.x * 128;
  int m0  = blockIdx.y * 128;
  int ksz = blockIdx.z;
  floatx4 acc[4][4];
  for (int i=0;i<4;i++) for (int j=0;j<4;j++) acc[i][j] = (floatx4){0.f,0.f,0.f,0.f};

  for (int kb=0; kb<3; kb++){
    int k0 = ksz*192 + kb*64;
    __syncthreads();
    #pragma unroll
    for (int i=0;i<4;i++){
      int idx = tid + 256*i;                 // 0..1023
      int row = idx >> 3, c8 = (idx & 7) * 8;
      int gm = m0 + row;
      float4 a0 = make_float4(0.f,0.f,0.f,0.f), a1 = a0;
      if (gm < 392){
        int k = k0 + c8;                     // chunk never straddles 768 boundary
        if (k < 768){
          float invc = 1.f / fmaxf(counts[gm], 1.f);
          a0 = *reinterpret_cast<const float4*>(&meansum[gm*768 + k]);
          a1 = *reinterpret_cast<const float4*>(&meansum[gm*768 + k + 4]);
          a0.x*=invc; a0.y*=invc; a0.z*=invc; a0.w*=invc;
          a1.x*=invc; a1.y*=invc; a1.z*=invc; a1.w*=invc;
        } else {
          a0 = *reinterpret_cast<const float4*>(&maxv[gm*768 + k - 768]);
          a1 = *reinterpret_cast<const float4*>(&maxv[gm*768 + k - 768 + 4]);
        }
      }
      ushort ua[8] = { f2bf(a0.x),f2bf(a0.y),f2bf(a0.z),f2bf(a0.w),
                       f2bf(a1.x),f2bf(a1.y),f2bf(a1.z),f2bf(a1.w) };
      *reinterpret_cast<uint4*>(&AL[row*72 + c8]) = *reinterpret_cast<uint4*>(ua);
      float4 b0 = *reinterpret_cast<const float4*>(&fw[(co0+row)*1536 + k0 + c8]);
      float4 b1 = *reinterpret_cast<const float4*>(&fw[(co0+row)*1536 + k0 + c8 + 4]);
      ushort ub[8] = { f2bf(b0.x),f2bf(b0.y),f2bf(b0.z),f2bf(b0.w),
                       f2bf(b1.x),f2bf(b1.y),f2bf(b1.z),f2bf(b1.w) };
      *reinterpret_cast<uint4*>(&BL[row*72 + c8]) = *reinterpret_cast<uint4*>(ub);
    }
    __syncthreads();
    #pragma unroll
    for (int ks=0; ks<64; ks+=32){
      short8 af[4], bfr[4];
      #pragma unroll
      for (int f=0; f<4; f++)
        af[f] = *reinterpret_cast<const short8*>(&AL[(wc*64+f*16+l15)*72 + ks + q*8]);
      #pragma unroll
      for (int f=0; f<4; f++)
        bfr[f] = *reinterpret_cast<const short8*>(&BL[(wp*64+f*16+l15)*72 + ks + q*8]);
      #pragma unroll
      for (int fm=0; fm<4; fm++)
        #pragma unroll
        for (int fn=0; fn<4; fn++)
          acc[fm][fn] = __builtin_amdgcn_mfma_f32_16x16x32_bf16(af[fm], bfr[fn], acc[fm][fn], 0,0,0);
    }
  }
  float* pp = &partial[(size_t)ksz * 301056];
  #pragma unroll
  for (int fm=0; fm<4; fm++){
    #pragma unroll
    for (int r2=0; r2<4; r2++){
      int m = m0 + wc*64 + fm*16 + q*4 + r2;
      if (m >= 392) continue;
      #pragma unroll
      for (int fn=0; fn<4; fn++){
        int co = co0 + wp*64 + fn*16 + l15;
        pp[(size_t)m*768 + co] = acc[fm][fn][r2];
      }
    }
  }
}

// ---------------- fusion epilogue: sum 8 K-split partials, bias, W_k scale, positional add
__global__ void fuse_ep_k(const float* __restrict__ partial, const float* __restrict__ fb,
                          const float* __restrict__ sims, const float* __restrict__ counts,
                          const float* __restrict__ cent, const float* __restrict__ pw,
                          const float* __restrict__ pb, float* __restrict__ out){
  int t = blockIdx.x*256 + threadIdx.x;    // 392*768 exactly
  int gm = t / 768, co = t % 768;
  float s = 0.f;
  #pragma unroll
  for (int k=0;k<8;k++) s += partial[(size_t)k*301056 + t];
  float wk = sims[gm] / fmaxf(counts[gm], 1.f);
  float cx = cent[gm*2 + 0] * (1.f/224.f);
  float cy = cent[gm*2 + 1] * (1.f/224.f);
  out[t] = (s + fb[co]) * wk + cx*pw[co*2] + cy*pw[co*2+1] + pb[co];
}

extern "C" void kernel_launch(void* const* d_in, const int* in_sizes, int n_in,
                              void* d_out, int out_size, void* d_ws, size_t ws_size,
                              hipStream_t stream){
  const float* img  = (const float*)d_in[0];
  const int*   seg  = (const int*)  d_in[1];
  const float* cent = (const float*)d_in[2];
  const float* c1w  = (const float*)d_in[3];
  const float* c1b  = (const float*)d_in[4];
  const float* bn1g = (const float*)d_in[5];
  const float* bn1b = (const float*)d_in[6];
  const float* bn1m = (const float*)d_in[7];
  const float* bn1v = (const float*)d_in[8];
  const float* c2w  = (const float*)d_in[9];
  const float* c2b  = (const float*)d_in[10];
  const float* bn2g = (const float*)d_in[11];
  const float* bn2b = (const float*)d_in[12];
  const float* bn2m = (const float*)d_in[13];
  const float* bn2v = (const float*)d_in[14];
  const float* ew   = (const float*)d_in[15];
  const float* pw   = (const float*)d_in[16];
  const float* pb   = (const float*)d_in[17];
  const float* fwp  = (const float*)d_in[18];
  const float* fbp  = (const float*)d_in[19];
  float* out = (float*)d_out;
  char* ws = (char*)d_ws;

  ushort* xbf    = (ushort*)(ws + 0);          //  12,845,056
  ushort* wt2    = (ushort*)(ws + 12845056);   //     884,736
  float*  bias2  = (float*) (ws + 13729792);   //       3,072
  float*  meansum= (float*) (ws + 13732864);   //   1,204,224  (memset region start)
  float*  maxv   = (float*) (ws + 14937088);   //   1,204,224
  float*  counts = (float*) (ws + 16141312);   //       1,568
  float*  sims   = (float*) (ws + 16142880);   //       1,568
  int*    scnt   = (int*)   (ws + 16144448);   //       3,136  (memset region end)
  int*    offs   = (int*)   (ws + 16147584);   //       3,200
  int*    curs   = (int*)   (ws + 16150784);   //       3,136
  int*    list   = (int*)   (ws + 16154112);   //     401,408  (global px indices)
  ushort* wA     = (ushort*)(ws + 16154112);   //       4,096 (aliases list; dead after conv1)
  float*  bias1  = (float*) (ws + 16158208);   //         256 (aliases list; dead after conv1)
  unsigned char* feats = (unsigned char*)(ws + 16555520);  // 77,070,336 (fp8 e4m3)
  float*  partial= (float*) (ws + 16555520);   //   9,633,792 (aliases feats; used after pooling)

  (void)hipMemsetAsync(ws + 13732864, 0, 2414720, stream);
  prep_edge_k<<<441, 256, 0, stream>>>(c2w, c2b, bn2g, bn2b, bn2m, bn2v, wt2, bias2,
                                       c1w, c1b, bn1g, bn1b, bn1m, bn1v, wA, bias1,
                                       img, seg, ew, out, counts, sims, scnt);
  conv1_scan_k<<<394, 256, 0, stream>>>(img, wA, bias1, xbf, scnt, offs, curs);
  conv2_scatter_k<<<dim3(392, 7), 256, 0, stream>>>(xbf, wt2, bias2, feats, seg, curs, list);
  pool_k<<<dim3(196, 8, 2), 192, 0, stream>>>(feats, list, offs, meansum, maxv);
  fusion_mfma_k<<<dim3(6, 4, 8), 256, 0, stream>>>(meansum, maxv, counts, fwp, partial);
  fuse_ep_k<<<1176, 256, 0, stream>>>(partial, fbp, sims, counts, cent, pw, pb, out);
}

// Round 8
// 260.622 us; speedup vs baseline: 4.1280x; 1.1659x over previous
//
#include <hip/hip_runtime.h>
#include <hip/hip_fp8.h>

#define B_ 2
#define H_ 224
#define W_ 224
#define HW_ 50176
#define E_ 768
#define M_ 196

typedef __attribute__((ext_vector_type(8))) short short8;
typedef __attribute__((ext_vector_type(8))) unsigned short ushort8;
typedef __attribute__((ext_vector_type(4))) float floatx4;

__device__ __forceinline__ float bf2f(ushort u){ return __uint_as_float(((unsigned)u)<<16); }
__device__ __forceinline__ ushort f2bf(float f){
  unsigned b = __float_as_uint(f);
  b += 0x7fffu + ((b>>16)&1u);
  return (ushort)(b>>16);
}
// HW fp8 (OCP e4m3 on gfx950): pack 4 relu'd floats -> 4 fp8 bytes in one uint
__device__ __forceinline__ unsigned pack4_fp8(float a, float b, float c, float d){
  int v = __builtin_amdgcn_cvt_pk_fp8_f32(a, b, 0, false);   // bits [15:0]
  v = __builtin_amdgcn_cvt_pk_fp8_f32(c, d, v, true);        // bits [31:16]
  return (unsigned)v;
}

// ---------------- merged prep + edge kernel (independent work, one dispatch):
// blocks 0..47:  fold BN2 into conv2 weights -> wt2[plane][co][8] (coalesced)
// block  48:     fold BN1 -> A[64 co][32 k]
// blocks 49..440: edge conv + gradient_map + similarity + per-seg stats
__global__ void prep_edge_k(const float* __restrict__ w2, const float* __restrict__ cb2,
                            const float* __restrict__ g2, const float* __restrict__ be2,
                            const float* __restrict__ mn2, const float* __restrict__ vr2,
                            ushort* __restrict__ wt2, float* __restrict__ bias2,
                            const float* __restrict__ w1, const float* __restrict__ cb1,
                            const float* __restrict__ g1, const float* __restrict__ be1,
                            const float* __restrict__ mn1, const float* __restrict__ vr1,
                            ushort* __restrict__ wA, float* __restrict__ bias1,
                            const float* __restrict__ img, const int* __restrict__ seg,
                            const float* __restrict__ ew, float* __restrict__ out,
                            float* __restrict__ counts, float* __restrict__ sims,
                            int* __restrict__ scnt){
  __shared__ ushort WT[9216];     // 16 co x 576 (co-major, src order)
  __shared__ float aux[196];      // invs[16] for prep2 | cnt for edge
  __shared__ float aux2[196];     // ssum for edge
  int tid = threadIdx.x;
  if (blockIdx.x < 48){
    int co0 = blockIdx.x * 16;
    if (tid < 16){
      float inv = g2[co0+tid] * rsqrtf(vr2[co0+tid] + 1e-5f);
      aux[tid] = inv;
      bias2[co0+tid] = cb2[co0+tid]*inv + be2[co0+tid] - mn2[co0+tid]*inv;
    }
    __syncthreads();
    #pragma unroll
    for (int j = 0; j < 36; j++){
      int idx = j*256 + tid;                 // 0..9215 = col*576 + (ci*9+tap)
      WT[idx] = f2bf(w2[(size_t)co0*576 + idx] * aux[idx/576]);
    }
    __syncthreads();
    #pragma unroll
    for (int j = 0; j < 5; j++){
      int o = j*256 + tid;                   // 0..1151
      if (o < 1152){
        int tapkc = o >> 4, col = o & 15;
        int tap = tapkc >> 3, kc = tapkc & 7;
        ushort tmp[8];
        #pragma unroll
        for (int e=0; e<8; e++)
          tmp[e] = WT[col*576 + (kc*8+e)*9 + tap];
        *reinterpret_cast<uint4*>(&wt2[(size_t)((tap*8 + kc)*768 + co0 + col)*8]) =
            *reinterpret_cast<const uint4*>(tmp);
      }
    }
    return;
  }
  if (blockIdx.x == 48){
    #pragma unroll
    for (int j = 0; j < 8; j++){
      int t = j*256 + tid;                   // 2048 exactly
      int co = t >> 5, k = t & 31;
      float inv = g1[co] * rsqrtf(vr1[co] + 1e-5f);
      float val = 0.f;
      if (k < 27){
        int tap = k / 3, ci = k % 3;
        val = w1[co*27 + ci*9 + tap] * inv;
      }
      wA[co*32 + k] = f2bf(val);
      if (k == 0) bias1[co] = cb1[co]*inv + be1[co] - mn1[co]*inv;
    }
    return;
  }
  // ---- edge path
  if (tid < 196){ aux[tid]=0.f; aux2[tid]=0.f; }
  __syncthreads();
  int p = (blockIdx.x-49)*256 + tid;
  int b = p / HW_; int r = p % HW_; int h = r / W_; int w = r % W_;
  float e0=0.f, e1=0.f;
  #pragma unroll
  for (int ky=0;ky<3;ky++){
    int hh=h+ky-1;
    #pragma unroll
    for (int kx=0;kx<3;kx++){
      int ww=w+kx-1;
      float gv=0.f;
      if (hh>=0&&hh<H_&&ww>=0&&ww<W_){
        int base = b*3*HW_ + hh*W_ + ww;
        gv=(img[base]+img[base+HW_]+img[base+2*HW_])*(1.f/3.f);
      }
      e0 += gv*ew[ky*3+kx];
      e1 += gv*ew[9+ky*3+kx];
    }
  }
  float gm = sqrtf(e0*e0+e1*e1+1e-8f);
  out[301056 + p] = gm;
  int sg = seg[p];
  out[401408 + p] = (float)sg;
  float sim = fminf(fmaxf(1.f-gm,0.f),1.f);
  atomicAdd(&aux[sg], 1.f);
  atomicAdd(&aux2[sg], sim);
  __syncthreads();
  if (tid < 196){
    int gid = b*196 + tid;
    float c = aux[tid];
    atomicAdd(&counts[gid], c);
    atomicAdd(&sims[gid], aux2[tid]);
    atomicAdd(&scnt[b*196+tid], (int)c);
  }
}

// ---------------- conv1 + BN1 + ReLU via bf16 MFMA (blocks 2..393);
// blocks 0..1: per-batch exclusive scan of segment counts (independent)
__launch_bounds__(256)
__global__ void conv1_scan_k(const float* __restrict__ img, const ushort* __restrict__ wA,
                             const float* __restrict__ bias1, ushort* __restrict__ xbf,
                             const int* __restrict__ scnt, int* __restrict__ offs,
                             int* __restrict__ curs){
  __shared__ float HL[3*18*20];          // fp32 halo, row pad 20 (also scan's a[])
  __shared__ ushort IC[256*40];          // im2col [px][32k pad40]
  __shared__ ushort AW[64*40];           // weights [co][32k pad40]
  __shared__ float b1s[64];
  int tid = threadIdx.x;
  if (blockIdx.x < 2){
    // ---- scan path
    int* a = reinterpret_cast<int*>(HL);
    int s = blockIdx.x;
    a[tid] = (tid<196)? scnt[s*196+tid] : 0;
    __syncthreads();
    for (int d=1; d<256; d<<=1){
      int v = a[tid];
      int u = (tid>=d)? a[tid-d] : 0;
      __syncthreads();
      a[tid] = v+u;
      __syncthreads();
    }
    if (tid<=196) offs[s*200+tid] = tid ? a[tid-1] : 0;
    if (tid<196)  curs[s*196+tid] = tid ? a[tid-1] : 0;
    return;
  }
  int bid = blockIdx.x - 2;
  int b = bid / 196, tile = bid % 196;
  int tr = tile / 14, tc = tile % 14;
  int h0 = tr*16, w0 = tc*16;
  for (int idx = tid; idx < 972; idx += 256){
    int ci = idx / 324, rem = idx % 324;
    int r = rem / 18, c = rem % 18;
    int hh = h0 + r - 1, ww = w0 + c - 1;
    float v = (hh>=0 && hh<H_ && ww>=0 && ww<W_) ? img[((b*3+ci)*H_+hh)*W_+ww] : 0.f;
    HL[ci*360 + r*20 + c] = v;
  }
  {
    int row = tid >> 2, cp = (tid&3)*8;
    uint4 v = *reinterpret_cast<const uint4*>(&wA[row*32 + cp]);
    *reinterpret_cast<uint4*>(&AW[row*40 + cp]) = v;
  }
  if (tid < 64) b1s[tid] = bias1[tid];
  __syncthreads();
  {
    int pr = tid >> 4, pc = tid & 15;
    ushort tmp[32];
    #pragma unroll
    for (int ky=0; ky<3; ky++)
      #pragma unroll
      for (int kx=0; kx<3; kx++)
        #pragma unroll
        for (int ci=0; ci<3; ci++)
          tmp[(ky*3+kx)*3+ci] = f2bf(HL[ci*360 + (pr+ky)*20 + (pc+kx)]);
    #pragma unroll
    for (int k=27; k<32; k++) tmp[k] = 0;
    #pragma unroll
    for (int j=0; j<4; j++)
      *reinterpret_cast<uint4*>(&IC[tid*40 + j*8]) = *reinterpret_cast<const uint4*>(&tmp[j*8]);
  }
  __syncthreads();
  int lane = tid & 63, wave = tid >> 6;
  int q = lane >> 4, l15 = lane & 15;
  short8 af[4], bfr[4];
  #pragma unroll
  for (int f=0; f<4; f++)
    af[f] = *reinterpret_cast<const short8*>(&AW[(f*16+l15)*40 + q*8]);
  #pragma unroll
  for (int f=0; f<4; f++)
    bfr[f] = *reinterpret_cast<const short8*>(&IC[(wave*64+f*16+l15)*40 + q*8]);
  floatx4 acc[4][4];
  #pragma unroll
  for (int fc=0; fc<4; fc++)
    #pragma unroll
    for (int fp=0; fp<4; fp++){
      floatx4 z = (floatx4){0.f,0.f,0.f,0.f};
      acc[fc][fp] = __builtin_amdgcn_mfma_f32_16x16x32_bf16(af[fc], bfr[fp], z, 0,0,0);
    }
  #pragma unroll
  for (int fp=0; fp<4; fp++){
    int pxl = wave*64 + fp*16 + l15;
    size_t gp = (size_t)b*HW_ + (size_t)(h0 + (pxl>>4))*W_ + (w0 + (pxl&15));
    #pragma unroll
    for (int fc=0; fc<4; fc++){
      int co4 = fc*16 + q*4;
      ushort o[4];
      #pragma unroll
      for (int r=0; r<4; r++) o[r] = f2bf(fmaxf(acc[fc][fp][r] + b1s[co4+r], 0.f));
      *reinterpret_cast<uint2*>(&xbf[gp*64 + co4]) = *reinterpret_cast<const uint2*>(o);
    }
  }
}

// ---------------- conv2 (dilated 3x3, 64->768) + BN2 + ReLU via bf16 MFMA implicit GEMM
// v11 FROZEN at ~108 us / MfmaUtil 34%: seven schedule variants (v4-v11: per-step
// barriers, counted vmcnt, 3-ring, reg-dbuf, barrier-free, half-cluster pipeline)
// across three tile geometries all converge 108-118 us -> m97-class structural
// ceiling for this geometry at 2 blocks/CU. Register law (v10): 512 VGPR/SIMD;
// at 2 waves/SIMD acc[4][8]=128 leaves arch<=128 -> only half-cluster pipelining fits.
// grid (392, 7): y==0 runs the scatter stage; y>=1 is conv2 with co0=(y-1)*128.
__launch_bounds__(256, 2)
__global__ void conv2_scatter_k(const ushort* __restrict__ xbf, const ushort* __restrict__ wt2,
                                const float* __restrict__ bias2, unsigned char* __restrict__ feats,
                                const int* __restrict__ seg, int* __restrict__ curs,
                                int* __restrict__ list){
  // XH: 8 planes x 400 px x 16B = 51200 B (write-once halo; epilogue reuses as EP)
  __shared__ ushort SM[25600];
  ushort* XH = SM;
  int tid = threadIdx.x;
  if (blockIdx.y == 0){
    // ---- scatter path: global pixel indices into per-(batch,segment) lists
    if (blockIdx.x < 392){
      int p = blockIdx.x*256 + tid;
      int b = p / HW_;
      int pos = atomicAdd(&curs[b*196+seg[p]], 1);
      list[b*HW_ + pos] = p;
    }
    return;
  }
  int lane = tid & 63, wave = tid >> 6;
  int wc = wave >> 1, wp = wave & 1;       // wc: co-half (64), wp: px-half (8 rows)
  int q = lane >> 4, l15 = lane & 15;
  int bt = blockIdx.x / 196, tile = blockIdx.x % 196;
  int tr = tile / 14, tc = tile % 14;
  int co0 = (blockIdx.y - 1) * 128;
  int h0 = tr*16, w0 = tc*16;

  // ---- stage X halo once: 400 px (20x20), thread=px reads full 128B pixel row
  for (int px = tid; px < 400; px += 256){
    int hr = px / 20, wcol = px % 20;
    int hh = h0 + hr - 2, ww = w0 + wcol - 2;
    bool ok = (hh>=0 && hh<H_ && ww>=0 && ww<W_);
    const uint4* src = reinterpret_cast<const uint4*>(&xbf[(((size_t)bt*H_+hh)*W_+ww)*64]);
    #pragma unroll
    for (int chl=0; chl<8; chl++){
      uint4 val = ok ? src[chl] : make_uint4(0u,0u,0u,0u);
      *reinterpret_cast<uint4*>(&XH[chl*3200 + px*8]) = val;
    }
  }
  __syncthreads();   // XH ready; ONLY barrier before the epilogue

  floatx4 acc[4][8];
  #pragma unroll
  for (int i=0;i<4;i++)
    #pragma unroll
    for (int j=0;j<8;j++) acc[i][j] = (floatx4){0.f,0.f,0.f,0.f};

  // per-lane invariant bases
  const int xb = q*3200 + wp*1280 + l15*8;   // X: + half*12800 + (dyr*20+dxr)*8 + fp*160
  // W global base: plane = hs*4 + q; af[f](hs) = wt2[((hs*4+q)*768 + co0 + wc*64 + f*16 + l15)*8]
  const ushort* wgl = wt2 + ((size_t)q*768 + (size_t)(co0 + wc*64 + l15))*8;

  short8 af[2][4], bxA[4], bxB[4];
  #pragma unroll
  for (int f=0; f<4; f++)
    af[0][f] = *reinterpret_cast<const short8*>(&wgl[f*128]);
  #pragma unroll
  for (int fp=0; fp<4; fp++)
    bxA[fp] = *reinterpret_cast<const short8*>(&XH[xb + fp*160]);    // xoff(0)=0

  #pragma unroll
  for (int hs = 0; hs < 18; hs++){
    const int cur = hs & 1, nxt = cur ^ 1;
    const int tap = hs >> 1, half = hs & 1;
    const int dyr = (tap/3)*2, dxr = (tap%3)*2;
    const int xoff = half*12800 + dyr*160 + dxr*8;       // compile-time (unrolled)
    // ---- phase A issue: af(hs+1) [global, ~2 clusters of cover] + bxB(hs)
    if (hs < 17){
      #pragma unroll
      for (int f=0; f<4; f++)
        af[nxt][f] = *reinterpret_cast<const short8*>(&wgl[(size_t)(hs+1)*24576 + f*128]);
    }
    #pragma unroll
    for (int fp=0; fp<4; fp++)
      bxB[fp] = *reinterpret_cast<const short8*>(&XH[xb + xoff + (4+fp)*160]);
    __builtin_amdgcn_sched_barrier(0);
    __builtin_amdgcn_s_setprio(1);
    #pragma unroll
    for (int fc=0; fc<4; fc++)
      #pragma unroll
      for (int fp=0; fp<4; fp++)
        acc[fc][fp] = __builtin_amdgcn_mfma_f32_16x16x32_bf16(af[cur][fc], bxA[fp],
                                                              acc[fc][fp], 0,0,0);
    __builtin_amdgcn_s_setprio(0);
    // ---- phase B issue: bxA(hs+1) (WAR vs cluster A is in program order -> safe)
    if (hs < 17){
      const int nh = hs + 1;
      const int ntap = nh >> 1, nhalf = nh & 1;
      const int nxoff = nhalf*12800 + ((ntap/3)*2)*160 + ((ntap%3)*2)*8;
      #pragma unroll
      for (int fp=0; fp<4; fp++)
        bxA[fp] = *reinterpret_cast<const short8*>(&XH[xb + nxoff + fp*160]);
    }
    __builtin_amdgcn_sched_barrier(0);
    __builtin_amdgcn_s_setprio(1);
    #pragma unroll
    for (int fc=0; fc<4; fc++)
      #pragma unroll
      for (int fp=0; fp<4; fp++)
        acc[fc][4+fp] = __builtin_amdgcn_mfma_f32_16x16x32_bf16(af[cur][fc], bxB[fp],
                                                                acc[fc][4+fp], 0,0,0);
    __builtin_amdgcn_s_setprio(0);
  }

  // ---- epilogue: bias+relu, HW fp8 pack -> LDS transpose -> coalesced stores.
  // XH dead; reuse SM as EP[256 px][34 uint] (pad 34: both sides max 2-way = free).
  __syncthreads();
  unsigned* EP = reinterpret_cast<unsigned*>(SM);    // 256*34*4 = 34,816 B <= 51,200 B
  #pragma unroll
  for (int fc=0; fc<4; fc++){
    float4 bs = *reinterpret_cast<const float4*>(&bias2[co0 + wc*64 + fc*16 + q*4]);
    int cslot = wc*16 + fc*4 + q;                    // uint slot = co_local/4 (0..31)
    #pragma unroll
    for (int fp=0; fp<8; fp++){
      int p_local = (wp*8 + fp)*16 + l15;            // 0..255
      EP[p_local*34 + cslot] = pack4_fp8(
          fmaxf(acc[fc][fp][0] + bs.x, 0.f), fmaxf(acc[fc][fp][1] + bs.y, 0.f),
          fmaxf(acc[fc][fp][2] + bs.z, 0.f), fmaxf(acc[fc][fp][3] + bs.w, 0.f));
    }
  }
  __syncthreads();
  {
    // 32 consecutive lanes cover one pixel's 128 contiguous bytes -> 4 cache
    // lines per store instruction (vs 64 with a 4B/lane stride-768 scatter).
    size_t gbase = ((size_t)bt*HW_ + (size_t)(tr*16)*W_ + tc*16)*768 + co0;
    int c = tid & 31, t5 = tid >> 5;
    #pragma unroll
    for (int j=0; j<32; j++){
      int px = j*8 + t5;                             // 0..255, each exactly once
      int rr = px >> 4, wcol = px & 15;
      *reinterpret_cast<unsigned*>(
        &feats[gbase + ((size_t)rr*W_ + wcol)*768 + c*4]) = EP[px*34 + c];
    }
  }
}

// ---------------- gather pooling v12: ATOMIC-FREE. Each (m,qu,b) block writes its
// partial sum (f32) and partial max (bf16 — exact for fp8 values) to a per-qu slot,
// written exactly once -> no memset, no L2 atomic serialization (was 4.8M device
// atomics = 16 per output address). Reduction over qu folds into fusion A-staging.
__global__ void pool_k(const unsigned char* __restrict__ feats, const int* __restrict__ list,
                       const int* __restrict__ offs, float* __restrict__ meansum_p,
                       ushort* __restrict__ maxv_p){
  int m = blockIdx.x, qu = blockIdx.y, b = blockIdx.z, tid = threadIdx.x;
  int base = offs[b*200+m], end = offs[b*200+m+1];
  int len = end - base;
  int b0 = base + ((len*qu) >> 3);
  int b1 = base + ((len*(qu+1)) >> 3);
  const int* lp = &list[b*HW_];
  int co4 = tid*4;
  float s0=0.f,s1=0.f,s2=0.f,s3=0.f;
  float m0=0.f,m1=0.f,m2=0.f,m3=0.f;
  int i = b0;
  // HW fp8->f32 (v_cvt_f32_fp8 byte-select)
  #define ACC(v) { \
    float f0=__builtin_amdgcn_cvt_f32_fp8((int)(v),0), f1=__builtin_amdgcn_cvt_f32_fp8((int)(v),1); \
    float f2=__builtin_amdgcn_cvt_f32_fp8((int)(v),2), f3=__builtin_amdgcn_cvt_f32_fp8((int)(v),3); \
    s0+=f0; s1+=f1; s2+=f2; s3+=f3; \
    m0=fmaxf(m0,f0); m1=fmaxf(m1,f1); m2=fmaxf(m2,f2); m3=fmaxf(m3,f3); }
  for (; i+3 < b1; i += 4){
    unsigned va = *reinterpret_cast<const unsigned*>(&feats[(size_t)lp[i  ]*768 + co4]);
    unsigned vb = *reinterpret_cast<const unsigned*>(&feats[(size_t)lp[i+1]*768 + co4]);
    unsigned vc = *reinterpret_cast<const unsigned*>(&feats[(size_t)lp[i+2]*768 + co4]);
    unsigned vd = *reinterpret_cast<const unsigned*>(&feats[(size_t)lp[i+3]*768 + co4]);
    ACC(va) ACC(vb) ACC(vc) ACC(vd)
  }
  for (; i < b1; i++){
    unsigned v = *reinterpret_cast<const unsigned*>(&feats[(size_t)lp[i]*768 + co4]);
    ACC(v)
  }
  #undef ACC
  int gs = b*196 + m;
  size_t slot = ((size_t)qu*392 + gs)*768 + co4;
  *reinterpret_cast<float4*>(&meansum_p[slot]) = make_float4(s0,s1,s2,s3);
  ushort mv[4] = { f2bf(m0), f2bf(m1), f2bf(m2), f2bf(m3) };   // exact (fp8 -> bf16)
  *reinterpret_cast<uint2*>(&maxv_p[slot]) = *reinterpret_cast<const uint2*>(mv);
}

// ---------------- fusion GEMM via bf16 MFMA, K-split; concat built inline from
// per-qu pool partials during A staging (sum x invc for mean; unsigned pk_max_u16
// over bf16 partials for max — monotonic for non-negative bf16, zero conversions)
__launch_bounds__(256)
__global__ void fusion_mfma_k(const float* __restrict__ meansum_p, const ushort* __restrict__ maxv_p,
                              const float* __restrict__ counts, const float* __restrict__ fw,
                              float* __restrict__ partial){
  __shared__ ushort SM2[2*128*72];      // AL (concat rows) | BL (fw rows)
  ushort* AL = SM2;
  ushort* BL = SM2 + 128*72;
  int tid = threadIdx.x;
  int lane = tid & 63, wave = tid >> 6;
  int wc = wave >> 1, wp = wave & 1;       // wc: m-half, wp: co-half
  int q = lane >> 4, l15 = lane & 15;
  int co0 = blockIdx.x * 128;
  int m0  = blockIdx.y * 128;
  int ksz = blockIdx.z;
  floatx4 acc[4][4];
  for (int i=0;i<4;i++) for (int j=0;j<4;j++) acc[i][j] = (floatx4){0.f,0.f,0.f,0.f};

  for (int kb=0; kb<3; kb++){
    int k0 = ksz*192 + kb*64;
    __syncthreads();
    #pragma unroll
    for (int i=0;i<4;i++){
      int idx = tid + 256*i;                 // 0..1023
      int row = idx >> 3, c8 = (idx & 7) * 8;
      int gm = m0 + row;
      uint4 aval = make_uint4(0u,0u,0u,0u);
      if (gm < 392){
        int k = k0 + c8;                     // chunk never straddles 768 boundary
        if (k < 768){
          float invc = 1.f / fmaxf(counts[gm], 1.f);
          float s[8] = {0.f,0.f,0.f,0.f,0.f,0.f,0.f,0.f};
          #pragma unroll
          for (int qu=0; qu<8; qu++){
            const float4* mp = reinterpret_cast<const float4*>(
                &meansum_p[((size_t)qu*392 + gm)*768 + k]);
            float4 t0 = mp[0], t1 = mp[1];
            s[0]+=t0.x; s[1]+=t0.y; s[2]+=t0.z; s[3]+=t0.w;
            s[4]+=t1.x; s[5]+=t1.y; s[6]+=t1.z; s[7]+=t1.w;
          }
          ushort ua[8];
          #pragma unroll
          for (int e=0; e<8; e++) ua[e] = f2bf(s[e]*invc);
          aval = *reinterpret_cast<const uint4*>(ua);
        } else {
          ushort8 mv = *reinterpret_cast<const ushort8*>(
              &maxv_p[((size_t)gm)*768 + (k-768)]);
          #pragma unroll
          for (int qu=1; qu<8; qu++){
            ushort8 t = *reinterpret_cast<const ushort8*>(
                &maxv_p[((size_t)qu*392 + gm)*768 + (k-768)]);
            mv = __builtin_elementwise_max(mv, t);
          }
          aval = *reinterpret_cast<const uint4*>(&mv);
        }
      }
      *reinterpret_cast<uint4*>(&AL[row*72 + c8]) = aval;
      float4 b0 = *reinterpret_cast<const float4*>(&fw[(co0+row)*1536 + k0 + c8]);
      float4 b1 = *reinterpret_cast<const float4*>(&fw[(co0+row)*1536 + k0 + c8 + 4]);
      ushort ub[8] = { f2bf(b0.x),f2bf(b0.y),f2bf(b0.z),f2bf(b0.w),
                       f2bf(b1.x),f2bf(b1.y),f2bf(b1.z),f2bf(b1.w) };
      *reinterpret_cast<uint4*>(&BL[row*72 + c8]) = *reinterpret_cast<uint4*>(ub);
    }
    __syncthreads();
    #pragma unroll
    for (int ks=0; ks<64; ks+=32){
      short8 af[4], bfr[4];
      #pragma unroll
      for (int f=0; f<4; f++)
        af[f] = *reinterpret_cast<const short8*>(&AL[(wc*64+f*16+l15)*72 + ks + q*8]);
      #pragma unroll
      for (int f=0; f<4; f++)
        bfr[f] = *reinterpret_cast<const short8*>(&BL[(wp*64+f*16+l15)*72 + ks + q*8]);
      #pragma unroll
      for (int fm=0; fm<4; fm++)
        #pragma unroll
        for (int fn=0; fn<4; fn++)
          acc[fm][fn] = __builtin_amdgcn_mfma_f32_16x16x32_bf16(af[fm], bfr[fn], acc[fm][fn], 0,0,0);
    }
  }
  float* pp = &partial[(size_t)ksz * 301056];
  #pragma unroll
  for (int fm=0; fm<4; fm++){
    #pragma unroll
    for (int r2=0; r2<4; r2++){
      int m = m0 + wc*64 + fm*16 + q*4 + r2;
      if (m >= 392) continue;
      #pragma unroll
      for (int fn=0; fn<4; fn++){
        int co = co0 + wp*64 + fn*16 + l15;
        pp[(size_t)m*768 + co] = acc[fm][fn][r2];
      }
    }
  }
}

// ---------------- fusion epilogue: sum 8 K-split partials, bias, W_k scale, positional add
__global__ void fuse_ep_k(const float* __restrict__ partial, const float* __restrict__ fb,
                          const float* __restrict__ sims, const float* __restrict__ counts,
                          const float* __restrict__ cent, const float* __restrict__ pw,
                          const float* __restrict__ pb, float* __restrict__ out){
  int t = blockIdx.x*256 + threadIdx.x;    // 392*768 exactly
  int gm = t / 768, co = t % 768;
  float s = 0.f;
  #pragma unroll
  for (int k=0;k<8;k++) s += partial[(size_t)k*301056 + t];
  float wk = sims[gm] / fmaxf(counts[gm], 1.f);
  float cx = cent[gm*2 + 0] * (1.f/224.f);
  float cy = cent[gm*2 + 1] * (1.f/224.f);
  out[t] = (s + fb[co]) * wk + cx*pw[co*2] + cy*pw[co*2+1] + pb[co];
}

extern "C" void kernel_launch(void* const* d_in, const int* in_sizes, int n_in,
                              void* d_out, int out_size, void* d_ws, size_t ws_size,
                              hipStream_t stream){
  const float* img  = (const float*)d_in[0];
  const int*   seg  = (const int*)  d_in[1];
  const float* cent = (const float*)d_in[2];
  const float* c1w  = (const float*)d_in[3];
  const float* c1b  = (const float*)d_in[4];
  const float* bn1g = (const float*)d_in[5];
  const float* bn1b = (const float*)d_in[6];
  const float* bn1m = (const float*)d_in[7];
  const float* bn1v = (const float*)d_in[8];
  const float* c2w  = (const float*)d_in[9];
  const float* c2b  = (const float*)d_in[10];
  const float* bn2g = (const float*)d_in[11];
  const float* bn2b = (const float*)d_in[12];
  const float* bn2m = (const float*)d_in[13];
  const float* bn2v = (const float*)d_in[14];
  const float* ew   = (const float*)d_in[15];
  const float* pw   = (const float*)d_in[16];
  const float* pb   = (const float*)d_in[17];
  const float* fwp  = (const float*)d_in[18];
  const float* fbp  = (const float*)d_in[19];
  float* out = (float*)d_out;
  char* ws = (char*)d_ws;

  ushort* xbf    = (ushort*)(ws + 0);          //  12,845,056 (dead after conv2)
  ushort* wt2    = (ushort*)(ws + 12845056);   //     884,736 (dead after conv2)
  float*  bias2  = (float*) (ws + 13729792);   //       3,072 (dead after conv2)
  // pool partials alias the dead xbf/wt2/bias2 region (time-disjoint):
  float*  meansum_p = (float*)(ws + 0);        //   9,633,792 = 8 qu x 392 x 768 f32
  ushort* maxv_p    = (ushort*)(ws + 9633792); //   4,816,896 = 8 qu x 392 x 768 bf16
  float*  counts = (float*) (ws + 16141312);   //       1,568  (memset region start)
  float*  sims   = (float*) (ws + 16142880);   //       1,568
  int*    scnt   = (int*)   (ws + 16144448);   //       3,136  (memset region end)
  int*    offs   = (int*)   (ws + 16147584);   //       3,200
  int*    curs   = (int*)   (ws + 16150784);   //       3,136
  int*    list   = (int*)   (ws + 16154112);   //     401,408  (global px indices)
  ushort* wA     = (ushort*)(ws + 16154112);   //       4,096 (aliases list; dead after conv1)
  float*  bias1  = (float*) (ws + 16158208);   //         256 (aliases list; dead after conv1)
  unsigned char* feats = (unsigned char*)(ws + 16555520);  // 77,070,336 (fp8 e4m3)
  float*  partial= (float*) (ws + 16555520);   //   9,633,792 (aliases feats; used after pooling)

  (void)hipMemsetAsync(ws + 16141312, 0, 6272, stream);   // counts+sims+scnt only
  prep_edge_k<<<441, 256, 0, stream>>>(c2w, c2b, bn2g, bn2b, bn2m, bn2v, wt2, bias2,
                                       c1w, c1b, bn1g, bn1b, bn1m, bn1v, wA, bias1,
                                       img, seg, ew, out, counts, sims, scnt);
  conv1_scan_k<<<394, 256, 0, stream>>>(img, wA, bias1, xbf, scnt, offs, curs);
  conv2_scatter_k<<<dim3(392, 7), 256, 0, stream>>>(xbf, wt2, bias2, feats, seg, curs, list);
  pool_k<<<dim3(196, 8, 2), 192, 0, stream>>>(feats, list, offs, meansum_p, maxv_p);
  fusion_mfma_k<<<dim3(6, 4, 8), 256, 0, stream>>>(meansum_p, maxv_p, counts, fwp, partial);
  fuse_ep_k<<<1176, 256, 0, stream>>>(partial, fbp, sims, counts, cent, pw, pb, out);
}

// Round 10
// 253.156 us; speedup vs baseline: 4.2498x; 1.0295x over previous
//
#include <hip/hip_runtime.h>
#include <hip/hip_fp8.h>

#define B_ 2
#define H_ 224
#define W_ 224
#define HW_ 50176
#define E_ 768
#define M_ 196

typedef __attribute__((ext_vector_type(8))) short short8;
typedef __attribute__((ext_vector_type(8))) unsigned short ushort8;
typedef __attribute__((ext_vector_type(4))) float floatx4;

__device__ __forceinline__ float bf2f(ushort u){ return __uint_as_float(((unsigned)u)<<16); }
__device__ __forceinline__ ushort f2bf(float f){
  unsigned b = __float_as_uint(f);
  b += 0x7fffu + ((b>>16)&1u);
  return (ushort)(b>>16);
}
// HW fp8 (OCP e4m3 on gfx950): pack 4 relu'd floats -> 4 fp8 bytes in one uint
__device__ __forceinline__ unsigned pack4_fp8(float a, float b, float c, float d){
  int v = __builtin_amdgcn_cvt_pk_fp8_f32(a, b, 0, false);   // bits [15:0]
  v = __builtin_amdgcn_cvt_pk_fp8_f32(c, d, v, true);        // bits [31:16]
  return (unsigned)v;
}

// ---------------- merged prep + edge kernel (independent work, one dispatch):
// blocks 0..47:  fold BN2 into conv2 weights -> wt2[plane][co][8] (coalesced)
// block  48:     fold BN1 -> A[64 co][32 k]
// blocks 49..440: edge conv (16x16 tiles, LDS-staged 18x18 gray halo) + stats
__global__ void prep_edge_k(const float* __restrict__ w2, const float* __restrict__ cb2,
                            const float* __restrict__ g2, const float* __restrict__ be2,
                            const float* __restrict__ mn2, const float* __restrict__ vr2,
                            ushort* __restrict__ wt2, float* __restrict__ bias2,
                            const float* __restrict__ w1, const float* __restrict__ cb1,
                            const float* __restrict__ g1, const float* __restrict__ be1,
                            const float* __restrict__ mn1, const float* __restrict__ vr1,
                            ushort* __restrict__ wA, float* __restrict__ bias1,
                            const float* __restrict__ img, const int* __restrict__ seg,
                            const float* __restrict__ ew, float* __restrict__ out,
                            float* __restrict__ counts, float* __restrict__ sims,
                            int* __restrict__ scnt){
  __shared__ ushort WT[9216];     // 16 co x 576 (prep2) | 324-float gray halo (edge)
  __shared__ float aux[196];      // invs[16] for prep2 | cnt for edge
  __shared__ float aux2[196];     // ssum for edge
  int tid = threadIdx.x;
  if (blockIdx.x < 48){
    int co0 = blockIdx.x * 16;
    if (tid < 16){
      float inv = g2[co0+tid] * rsqrtf(vr2[co0+tid] + 1e-5f);
      aux[tid] = inv;
      bias2[co0+tid] = cb2[co0+tid]*inv + be2[co0+tid] - mn2[co0+tid]*inv;
    }
    __syncthreads();
    #pragma unroll
    for (int j = 0; j < 36; j++){
      int idx = j*256 + tid;                 // 0..9215 = col*576 + (ci*9+tap)
      WT[idx] = f2bf(w2[(size_t)co0*576 + idx] * aux[idx/576]);
    }
    __syncthreads();
    #pragma unroll
    for (int j = 0; j < 5; j++){
      int o = j*256 + tid;                   // 0..1151
      if (o < 1152){
        int tapkc = o >> 4, col = o & 15;
        int tap = tapkc >> 3, kc = tapkc & 7;
        ushort tmp[8];
        #pragma unroll
        for (int e=0; e<8; e++)
          tmp[e] = WT[col*576 + (kc*8+e)*9 + tap];
        *reinterpret_cast<uint4*>(&wt2[(size_t)((tap*8 + kc)*768 + co0 + col)*8]) =
            *reinterpret_cast<const uint4*>(tmp);
      }
    }
    return;
  }
  if (blockIdx.x == 48){
    #pragma unroll
    for (int j = 0; j < 8; j++){
      int t = j*256 + tid;                   // 2048 exactly
      int co = t >> 5, k = t & 31;
      float inv = g1[co] * rsqrtf(vr1[co] + 1e-5f);
      float val = 0.f;
      if (k < 27){
        int tap = k / 3, ci = k % 3;
        val = w1[co*27 + ci*9 + tap] * inv;
      }
      wA[co*32 + k] = f2bf(val);
      if (k == 0) bias1[co] = cb1[co]*inv + be1[co] - mn1[co]*inv;
    }
    return;
  }
  // ---- edge path: 16x16 tile, gray halo staged once in LDS (was 27 global
  // loads/thread recomputing gray 9x; now ~4 loads/thread).
  // R8 bug fix: halo has 324 elements but block has 256 threads -> MUST be a
  // strided loop (R8's `if (tid<324)` left GR[256..323] uninitialized).
  float* GR = reinterpret_cast<float*>(WT);          // 324 floats <= 9216 ushort
  if (tid < 196){ aux[tid]=0.f; aux2[tid]=0.f; }
  int et = blockIdx.x - 49;                          // 0..391
  int b = et / 196, t196 = et % 196;
  int tr = t196 / 14, tc = t196 % 14;
  int h0 = tr*16, w0 = tc*16;
  for (int i = tid; i < 324; i += 256){
    int r = i / 18, c = i % 18;
    int hh = h0 + r - 1, ww = w0 + c - 1;
    float g = 0.f;
    if (hh>=0 && hh<H_ && ww>=0 && ww<W_){
      int base = b*3*HW_ + hh*W_ + ww;
      g = (img[base] + img[base+HW_] + img[base+2*HW_]) * (1.f/3.f);
    }
    GR[i] = g;
  }
  __syncthreads();
  int pr = tid >> 4, pc = tid & 15;
  float e0=0.f, e1=0.f;
  #pragma unroll
  for (int ky=0;ky<3;ky++)
    #pragma unroll
    for (int kx=0;kx<3;kx++){
      float gv = GR[(pr+ky)*18 + (pc+kx)];
      e0 += gv*ew[ky*3+kx];
      e1 += gv*ew[9+ky*3+kx];
    }
  float gm = sqrtf(e0*e0+e1*e1+1e-8f);
  int p = b*HW_ + (h0+pr)*W_ + (w0+pc);
  out[301056 + p] = gm;
  int sg = seg[p];
  out[401408 + p] = (float)sg;
  float sim = fminf(fmaxf(1.f-gm,0.f),1.f);
  atomicAdd(&aux[sg], 1.f);
  atomicAdd(&aux2[sg], sim);
  __syncthreads();
  if (tid < 196){
    int gid = b*196 + tid;
    float c = aux[tid];
    atomicAdd(&counts[gid], c);
    atomicAdd(&sims[gid], aux2[tid]);
    atomicAdd(&scnt[b*196+tid], (int)c);
  }
}

// ---------------- conv1 + BN1 + ReLU via bf16 MFMA (blocks 2..393);
// blocks 0..1: per-batch exclusive scan of segment counts (independent)
__launch_bounds__(256)
__global__ void conv1_scan_k(const float* __restrict__ img, const ushort* __restrict__ wA,
                             const float* __restrict__ bias1, ushort* __restrict__ xbf,
                             const int* __restrict__ scnt, int* __restrict__ offs,
                             int* __restrict__ curs){
  __shared__ float HL[3*18*20];          // fp32 halo, row pad 20 (also scan's a[])
  __shared__ ushort IC[256*40];          // im2col [px][32k pad40]
  __shared__ ushort AW[64*40];           // weights [co][32k pad40]
  __shared__ float b1s[64];
  int tid = threadIdx.x;
  if (blockIdx.x < 2){
    // ---- scan path
    int* a = reinterpret_cast<int*>(HL);
    int s = blockIdx.x;
    a[tid] = (tid<196)? scnt[s*196+tid] : 0;
    __syncthreads();
    for (int d=1; d<256; d<<=1){
      int v = a[tid];
      int u = (tid>=d)? a[tid-d] : 0;
      __syncthreads();
      a[tid] = v+u;
      __syncthreads();
    }
    if (tid<=196) offs[s*200+tid] = tid ? a[tid-1] : 0;
    if (tid<196)  curs[s*196+tid] = tid ? a[tid-1] : 0;
    return;
  }
  int bid = blockIdx.x - 2;
  int b = bid / 196, tile = bid % 196;
  int tr = tile / 14, tc = tile % 14;
  int h0 = tr*16, w0 = tc*16;
  for (int idx = tid; idx < 972; idx += 256){
    int ci = idx / 324, rem = idx % 324;
    int r = rem / 18, c = rem % 18;
    int hh = h0 + r - 1, ww = w0 + c - 1;
    float v = (hh>=0 && hh<H_ && ww>=0 && ww<W_) ? img[((b*3+ci)*H_+hh)*W_+ww] : 0.f;
    HL[ci*360 + r*20 + c] = v;
  }
  {
    int row = tid >> 2, cp = (tid&3)*8;
    uint4 v = *reinterpret_cast<const uint4*>(&wA[row*32 + cp]);
    *reinterpret_cast<uint4*>(&AW[row*40 + cp]) = v;
  }
  if (tid < 64) b1s[tid] = bias1[tid];
  __syncthreads();
  {
    int pr = tid >> 4, pc = tid & 15;
    ushort tmp[32];
    #pragma unroll
    for (int ky=0; ky<3; ky++)
      #pragma unroll
      for (int kx=0; kx<3; kx++)
        #pragma unroll
        for (int ci=0; ci<3; ci++)
          tmp[(ky*3+kx)*3+ci] = f2bf(HL[ci*360 + (pr+ky)*20 + (pc+kx)]);
    #pragma unroll
    for (int k=27; k<32; k++) tmp[k] = 0;
    #pragma unroll
    for (int j=0; j<4; j++)
      *reinterpret_cast<uint4*>(&IC[tid*40 + j*8]) = *reinterpret_cast<const uint4*>(&tmp[j*8]);
  }
  __syncthreads();
  int lane = tid & 63, wave = tid >> 6;
  int q = lane >> 4, l15 = lane & 15;
  short8 af[4], bfr[4];
  #pragma unroll
  for (int f=0; f<4; f++)
    af[f] = *reinterpret_cast<const short8*>(&AW[(f*16+l15)*40 + q*8]);
  #pragma unroll
  for (int f=0; f<4; f++)
    bfr[f] = *reinterpret_cast<const short8*>(&IC[(wave*64+f*16+l15)*40 + q*8]);
  floatx4 acc[4][4];
  #pragma unroll
  for (int fc=0; fc<4; fc++)
    #pragma unroll
    for (int fp=0; fp<4; fp++){
      floatx4 z = (floatx4){0.f,0.f,0.f,0.f};
      acc[fc][fp] = __builtin_amdgcn_mfma_f32_16x16x32_bf16(af[fc], bfr[fp], z, 0,0,0);
    }
  #pragma unroll
  for (int fp=0; fp<4; fp++){
    int pxl = wave*64 + fp*16 + l15;
    size_t gp = (size_t)b*HW_ + (size_t)(h0 + (pxl>>4))*W_ + (w0 + (pxl&15));
    #pragma unroll
    for (int fc=0; fc<4; fc++){
      int co4 = fc*16 + q*4;
      ushort o[4];
      #pragma unroll
      for (int r=0; r<4; r++) o[r] = f2bf(fmaxf(acc[fc][fp][r] + b1s[co4+r], 0.f));
      *reinterpret_cast<uint2*>(&xbf[gp*64 + co4]) = *reinterpret_cast<const uint2*>(o);
    }
  }
}

// ---------------- conv2 (dilated 3x3, 64->768) + BN2 + ReLU via bf16 MFMA implicit GEMM
// v11 FROZEN at ~108 us / MfmaUtil 34%: seven schedule variants (v4-v11) across three
// tile geometries all converge 108-118 us -> m97-class structural ceiling for this
// geometry at 2 blocks/CU. Register law (v10): 512 VGPR/SIMD; at 2 waves/SIMD
// acc[4][8]=128 leaves arch<=128 -> only half-cluster pipelining fits.
// grid (392, 7): y==0 runs the scatter stage; y>=1 is conv2 with co0=(y-1)*128.
__launch_bounds__(256, 2)
__global__ void conv2_scatter_k(const ushort* __restrict__ xbf, const ushort* __restrict__ wt2,
                                const float* __restrict__ bias2, unsigned char* __restrict__ feats,
                                const int* __restrict__ seg, int* __restrict__ curs,
                                int* __restrict__ list){
  // XH: 8 planes x 400 px x 16B = 51200 B (write-once halo; epilogue reuses as EP)
  __shared__ ushort SM[25600];
  ushort* XH = SM;
  int tid = threadIdx.x;
  if (blockIdx.y == 0){
    // ---- scatter path: global pixel indices into per-(batch,segment) lists
    if (blockIdx.x < 392){
      int p = blockIdx.x*256 + tid;
      int b = p / HW_;
      int pos = atomicAdd(&curs[b*196+seg[p]], 1);
      list[b*HW_ + pos] = p;
    }
    return;
  }
  int lane = tid & 63, wave = tid >> 6;
  int wc = wave >> 1, wp = wave & 1;       // wc: co-half (64), wp: px-half (8 rows)
  int q = lane >> 4, l15 = lane & 15;
  int bt = blockIdx.x / 196, tile = blockIdx.x % 196;
  int tr = tile / 14, tc = tile % 14;
  int co0 = (blockIdx.y - 1) * 128;
  int h0 = tr*16, w0 = tc*16;

  // ---- stage X halo once: 400 px (20x20), thread=px reads full 128B pixel row
  for (int px = tid; px < 400; px += 256){
    int hr = px / 20, wcol = px % 20;
    int hh = h0 + hr - 2, ww = w0 + wcol - 2;
    bool ok = (hh>=0 && hh<H_ && ww>=0 && ww<W_);
    const uint4* src = reinterpret_cast<const uint4*>(&xbf[(((size_t)bt*H_+hh)*W_+ww)*64]);
    #pragma unroll
    for (int chl=0; chl<8; chl++){
      uint4 val = ok ? src[chl] : make_uint4(0u,0u,0u,0u);
      *reinterpret_cast<uint4*>(&XH[chl*3200 + px*8]) = val;
    }
  }
  __syncthreads();   // XH ready; ONLY barrier before the epilogue

  floatx4 acc[4][8];
  #pragma unroll
  for (int i=0;i<4;i++)
    #pragma unroll
    for (int j=0;j<8;j++) acc[i][j] = (floatx4){0.f,0.f,0.f,0.f};

  // per-lane invariant bases
  const int xb = q*3200 + wp*1280 + l15*8;   // X: + half*12800 + (dyr*20+dxr)*8 + fp*160
  // W global base: plane = hs*4 + q; af[f](hs) = wt2[((hs*4+q)*768 + co0 + wc*64 + f*16 + l15)*8]
  const ushort* wgl = wt2 + ((size_t)q*768 + (size_t)(co0 + wc*64 + l15))*8;

  short8 af[2][4], bxA[4], bxB[4];
  #pragma unroll
  for (int f=0; f<4; f++)
    af[0][f] = *reinterpret_cast<const short8*>(&wgl[f*128]);
  #pragma unroll
  for (int fp=0; fp<4; fp++)
    bxA[fp] = *reinterpret_cast<const short8*>(&XH[xb + fp*160]);    // xoff(0)=0

  #pragma unroll
  for (int hs = 0; hs < 18; hs++){
    const int cur = hs & 1, nxt = cur ^ 1;
    const int tap = hs >> 1, half = hs & 1;
    const int dyr = (tap/3)*2, dxr = (tap%3)*2;
    const int xoff = half*12800 + dyr*160 + dxr*8;       // compile-time (unrolled)
    // ---- phase A issue: af(hs+1) [global, ~2 clusters of cover] + bxB(hs)
    if (hs < 17){
      #pragma unroll
      for (int f=0; f<4; f++)
        af[nxt][f] = *reinterpret_cast<const short8*>(&wgl[(size_t)(hs+1)*24576 + f*128]);
    }
    #pragma unroll
    for (int fp=0; fp<4; fp++)
      bxB[fp] = *reinterpret_cast<const short8*>(&XH[xb + xoff + (4+fp)*160]);
    __builtin_amdgcn_sched_barrier(0);
    __builtin_amdgcn_s_setprio(1);
    #pragma unroll
    for (int fc=0; fc<4; fc++)
      #pragma unroll
      for (int fp=0; fp<4; fp++)
        acc[fc][fp] = __builtin_amdgcn_mfma_f32_16x16x32_bf16(af[cur][fc], bxA[fp],
                                                              acc[fc][fp], 0,0,0);
    __builtin_amdgcn_s_setprio(0);
    // ---- phase B issue: bxA(hs+1) (WAR vs cluster A is in program order -> safe)
    if (hs < 17){
      const int nh = hs + 1;
      const int ntap = nh >> 1, nhalf = nh & 1;
      const int nxoff = nhalf*12800 + ((ntap/3)*2)*160 + ((ntap%3)*2)*8;
      #pragma unroll
      for (int fp=0; fp<4; fp++)
        bxA[fp] = *reinterpret_cast<const short8*>(&XH[xb + nxoff + fp*160]);
    }
    __builtin_amdgcn_sched_barrier(0);
    __builtin_amdgcn_s_setprio(1);
    #pragma unroll
    for (int fc=0; fc<4; fc++)
      #pragma unroll
      for (int fp=0; fp<4; fp++)
        acc[fc][4+fp] = __builtin_amdgcn_mfma_f32_16x16x32_bf16(af[cur][fc], bxB[fp],
                                                                acc[fc][4+fp], 0,0,0);
    __builtin_amdgcn_s_setprio(0);
  }

  // ---- epilogue: bias+relu, HW fp8 pack -> LDS transpose -> coalesced stores.
  // XH dead; reuse SM as EP[256 px][34 uint] (pad 34: both sides max 2-way = free).
  __syncthreads();
  unsigned* EP = reinterpret_cast<unsigned*>(SM);    // 256*34*4 = 34,816 B <= 51,200 B
  #pragma unroll
  for (int fc=0; fc<4; fc++){
    float4 bs = *reinterpret_cast<const float4*>(&bias2[co0 + wc*64 + fc*16 + q*4]);
    int cslot = wc*16 + fc*4 + q;                    // uint slot = co_local/4 (0..31)
    #pragma unroll
    for (int fp=0; fp<8; fp++){
      int p_local = (wp*8 + fp)*16 + l15;            // 0..255
      EP[p_local*34 + cslot] = pack4_fp8(
          fmaxf(acc[fc][fp][0] + bs.x, 0.f), fmaxf(acc[fc][fp][1] + bs.y, 0.f),
          fmaxf(acc[fc][fp][2] + bs.z, 0.f), fmaxf(acc[fc][fp][3] + bs.w, 0.f));
    }
  }
  __syncthreads();
  {
    // 32 consecutive lanes cover one pixel's 128 contiguous bytes -> 4 cache
    // lines per store instruction (vs 64 with a 4B/lane stride-768 scatter).
    size_t gbase = ((size_t)bt*HW_ + (size_t)(tr*16)*W_ + tc*16)*768 + co0;
    int c = tid & 31, t5 = tid >> 5;
    #pragma unroll
    for (int j=0; j<32; j++){
      int px = j*8 + t5;                             // 0..255, each exactly once
      int rr = px >> 4, wcol = px & 15;
      *reinterpret_cast<unsigned*>(
        &feats[gbase + ((size_t)rr*W_ + wcol)*768 + c*4]) = EP[px*34 + c];
    }
  }
}

// ---------------- gather pooling: ATOMIC-FREE. Each (m,qu,b) block writes its
// partial sum (f32) and partial max (bf16 — exact for fp8 values) to a per-qu slot.
__global__ void pool_k(const unsigned char* __restrict__ feats, const int* __restrict__ list,
                       const int* __restrict__ offs, float* __restrict__ meansum_p,
                       ushort* __restrict__ maxv_p){
  int m = blockIdx.x, qu = blockIdx.y, b = blockIdx.z, tid = threadIdx.x;
  int base = offs[b*200+m], end = offs[b*200+m+1];
  int len = end - base;
  int b0 = base + ((len*qu) >> 3);
  int b1 = base + ((len*(qu+1)) >> 3);
  const int* lp = &list[b*HW_];
  int co4 = tid*4;
  float s0=0.f,s1=0.f,s2=0.f,s3=0.f;
  float m0=0.f,m1=0.f,m2=0.f,m3=0.f;
  int i = b0;
  // HW fp8->f32 (v_cvt_f32_fp8 byte-select)
  #define ACC(v) { \
    float f0=__builtin_amdgcn_cvt_f32_fp8((int)(v),0), f1=__builtin_amdgcn_cvt_f32_fp8((int)(v),1); \
    float f2=__builtin_amdgcn_cvt_f32_fp8((int)(v),2), f3=__builtin_amdgcn_cvt_f32_fp8((int)(v),3); \
    s0+=f0; s1+=f1; s2+=f2; s3+=f3; \
    m0=fmaxf(m0,f0); m1=fmaxf(m1,f1); m2=fmaxf(m2,f2); m3=fmaxf(m3,f3); }
  for (; i+3 < b1; i += 4){
    unsigned va = *reinterpret_cast<const unsigned*>(&feats[(size_t)lp[i  ]*768 + co4]);
    unsigned vb = *reinterpret_cast<const unsigned*>(&feats[(size_t)lp[i+1]*768 + co4]);
    unsigned vc = *reinterpret_cast<const unsigned*>(&feats[(size_t)lp[i+2]*768 + co4]);
    unsigned vd = *reinterpret_cast<const unsigned*>(&feats[(size_t)lp[i+3]*768 + co4]);
    ACC(va) ACC(vb) ACC(vc) ACC(vd)
  }
  for (; i < b1; i++){
    unsigned v = *reinterpret_cast<const unsigned*>(&feats[(size_t)lp[i]*768 + co4]);
    ACC(v)
  }
  #undef ACC
  int gs = b*196 + m;
  size_t slot = ((size_t)qu*392 + gs)*768 + co4;
  *reinterpret_cast<float4*>(&meansum_p[slot]) = make_float4(s0,s1,s2,s3);
  ushort mv[4] = { f2bf(m0), f2bf(m1), f2bf(m2), f2bf(m3) };   // exact (fp8 -> bf16)
  *reinterpret_cast<uint2*>(&maxv_p[slot]) = *reinterpret_cast<const uint2*>(mv);
}

// ---------------- fold 8-qu partials ONCE into bf16 concat cc[392][1536]
// (v12 did this inline in fusion A-staging, replayed by all 6 co0 blocks = ~87 MB
// of redundant reads; here it's 14.5 MB read / 1.2 MB write, exactly once).
__global__ void reduce_pool_k(const float* __restrict__ meansum_p,
                              const ushort* __restrict__ maxv_p,
                              const float* __restrict__ counts,
                              ushort* __restrict__ cc){
  int t = blockIdx.x*256 + threadIdx.x;      // 294*256 = 75264 = 392*192 exactly
  int gm = t / 192;
  int c8 = (t % 192) * 8;                    // 0..1528, chunk of 8
  ushort ua[8];
  if (c8 < 768){
    float s[8] = {0.f,0.f,0.f,0.f,0.f,0.f,0.f,0.f};
    #pragma unroll
    for (int qu=0; qu<8; qu++){
      const float4* mp = reinterpret_cast<const float4*>(
          &meansum_p[((size_t)qu*392 + gm)*768 + c8]);
      float4 t0 = mp[0], t1 = mp[1];
      s[0]+=t0.x; s[1]+=t0.y; s[2]+=t0.z; s[3]+=t0.w;
      s[4]+=t1.x; s[5]+=t1.y; s[6]+=t1.z; s[7]+=t1.w;
    }
    float invc = 1.f / fmaxf(counts[gm], 1.f);
    #pragma unroll
    for (int e=0; e<8; e++) ua[e] = f2bf(s[e]*invc);
  } else {
    ushort8 mv = *reinterpret_cast<const ushort8*>(&maxv_p[(size_t)gm*768 + (c8-768)]);
    #pragma unroll
    for (int qu=1; qu<8; qu++){
      ushort8 tt = *reinterpret_cast<const ushort8*>(
          &maxv_p[((size_t)qu*392 + gm)*768 + (c8-768)]);
      mv = __builtin_elementwise_max(mv, tt);   // unsigned max == fmax for bf16 >= 0
    }
    *reinterpret_cast<ushort8*>(ua) = mv;
  }
  *reinterpret_cast<uint4*>(&cc[(size_t)gm*1536 + c8]) = *reinterpret_cast<const uint4*>(ua);
}

// ---------------- fusion GEMM via bf16 MFMA, K-split; A rows come straight from cc
__launch_bounds__(256)
__global__ void fusion_mfma_k(const ushort* __restrict__ cc, const float* __restrict__ fw,
                              float* __restrict__ partial){
  __shared__ ushort SM2[2*128*72];      // AL (concat rows) | BL (fw rows)
  ushort* AL = SM2;
  ushort* BL = SM2 + 128*72;
  int tid = threadIdx.x;
  int lane = tid & 63, wave = tid >> 6;
  int wc = wave >> 1, wp = wave & 1;       // wc: m-half, wp: co-half
  int q = lane >> 4, l15 = lane & 15;
  int co0 = blockIdx.x * 128;
  int m0  = blockIdx.y * 128;
  int ksz = blockIdx.z;
  floatx4 acc[4][4];
  for (int i=0;i<4;i++) for (int j=0;j<4;j++) acc[i][j] = (floatx4){0.f,0.f,0.f,0.f};

  for (int kb=0; kb<3; kb++){
    int k0 = ksz*192 + kb*64;
    __syncthreads();
    #pragma unroll
    for (int i=0;i<4;i++){
      int idx = tid + 256*i;                 // 0..1023
      int row = idx >> 3, c8 = (idx & 7) * 8;
      int gm = m0 + row;
      uint4 aval = make_uint4(0u,0u,0u,0u);
      if (gm < 392)
        aval = *reinterpret_cast<const uint4*>(&cc[(size_t)gm*1536 + k0 + c8]);
      *reinterpret_cast<uint4*>(&AL[row*72 + c8]) = aval;
      float4 b0 = *reinterpret_cast<const float4*>(&fw[(co0+row)*1536 + k0 + c8]);
      float4 b1 = *reinterpret_cast<const float4*>(&fw[(co0+row)*1536 + k0 + c8 + 4]);
      ushort ub[8] = { f2bf(b0.x),f2bf(b0.y),f2bf(b0.z),f2bf(b0.w),
                       f2bf(b1.x),f2bf(b1.y),f2bf(b1.z),f2bf(b1.w) };
      *reinterpret_cast<uint4*>(&BL[row*72 + c8]) = *reinterpret_cast<uint4*>(ub);
    }
    __syncthreads();
    #pragma unroll
    for (int ks=0; ks<64; ks+=32){
      short8 af[4], bfr[4];
      #pragma unroll
      for (int f=0; f<4; f++)
        af[f] = *reinterpret_cast<const short8*>(&AL[(wc*64+f*16+l15)*72 + ks + q*8]);
      #pragma unroll
      for (int f=0; f<4; f++)
        bfr[f] = *reinterpret_cast<const short8*>(&BL[(wp*64+f*16+l15)*72 + ks + q*8]);
      #pragma unroll
      for (int fm=0; fm<4; fm++)
        #pragma unroll
        for (int fn=0; fn<4; fn++)
          acc[fm][fn] = __builtin_amdgcn_mfma_f32_16x16x32_bf16(af[fm], bfr[fn], acc[fm][fn], 0,0,0);
    }
  }
  float* pp = &partial[(size_t)ksz * 301056];
  #pragma unroll
  for (int fm=0; fm<4; fm++){
    #pragma unroll
    for (int r2=0; r2<4; r2++){
      int m = m0 + wc*64 + fm*16 + q*4 + r2;
      if (m >= 392) continue;
      #pragma unroll
      for (int fn=0; fn<4; fn++){
        int co = co0 + wp*64 + fn*16 + l15;
        pp[(size_t)m*768 + co] = acc[fm][fn][r2];
      }
    }
  }
}

// ---------------- fusion epilogue: sum 8 K-split partials, bias, W_k scale, positional add
__global__ void fuse_ep_k(const float* __restrict__ partial, const float* __restrict__ fb,
                          const float* __restrict__ sims, const float* __restrict__ counts,
                          const float* __restrict__ cent, const float* __restrict__ pw,
                          const float* __restrict__ pb, float* __restrict__ out){
  int t = blockIdx.x*256 + threadIdx.x;    // 392*768 exactly
  int gm = t / 768, co = t % 768;
  float s = 0.f;
  #pragma unroll
  for (int k=0;k<8;k++) s += partial[(size_t)k*301056 + t];
  float wk = sims[gm] / fmaxf(counts[gm], 1.f);
  float cx = cent[gm*2 + 0] * (1.f/224.f);
  float cy = cent[gm*2 + 1] * (1.f/224.f);
  out[t] = (s + fb[co]) * wk + cx*pw[co*2] + cy*pw[co*2+1] + pb[co];
}

extern "C" void kernel_launch(void* const* d_in, const int* in_sizes, int n_in,
                              void* d_out, int out_size, void* d_ws, size_t ws_size,
                              hipStream_t stream){
  const float* img  = (const float*)d_in[0];
  const int*   seg  = (const int*)  d_in[1];
  const float* cent = (const float*)d_in[2];
  const float* c1w  = (const float*)d_in[3];
  const float* c1b  = (const float*)d_in[4];
  const float* bn1g = (const float*)d_in[5];
  const float* bn1b = (const float*)d_in[6];
  const float* bn1m = (const float*)d_in[7];
  const float* bn1v = (const float*)d_in[8];
  const float* c2w  = (const float*)d_in[9];
  const float* c2b  = (const float*)d_in[10];
  const float* bn2g = (const float*)d_in[11];
  const float* bn2b = (const float*)d_in[12];
  const float* bn2m = (const float*)d_in[13];
  const float* bn2v = (const float*)d_in[14];
  const float* ew   = (const float*)d_in[15];
  const float* pw   = (const float*)d_in[16];
  const float* pb   = (const float*)d_in[17];
  const float* fwp  = (const float*)d_in[18];
  const float* fbp  = (const float*)d_in[19];
  float* out = (float*)d_out;
  char* ws = (char*)d_ws;

  ushort* xbf    = (ushort*)(ws + 0);          //  12,845,056 (dead after conv2)
  ushort* wt2    = (ushort*)(ws + 12845056);   //     884,736 (dead after conv2)
  float*  bias2  = (float*) (ws + 13729792);   //       3,072 (dead after conv2)
  // pool partials + concat alias the dead xbf/wt2/bias2 region (time-disjoint):
  float*  meansum_p = (float*)(ws + 0);        //   9,633,792 = 8 qu x 392 x 768 f32
  ushort* maxv_p    = (ushort*)(ws + 9633792); //   4,816,896 = 8 qu x 392 x 768 bf16
  ushort* cc        = (ushort*)(ws + 14450688);//   1,204,224 = 392 x 1536 bf16
  float*  counts = (float*) (ws + 16141312);   //       1,568  (memset region start)
  float*  sims   = (float*) (ws + 16142880);   //       1,568
  int*    scnt   = (int*)   (ws + 16144448);   //       3,136  (memset region end)
  int*    offs   = (int*)   (ws + 16147584);   //       3,200
  int*    curs   = (int*)   (ws + 16150784);   //       3,136
  int*    list   = (int*)   (ws + 16154112);   //     401,408  (global px indices)
  ushort* wA     = (ushort*)(ws + 16154112);   //       4,096 (aliases list; dead after conv1)
  float*  bias1  = (float*) (ws + 16158208);   //         256 (aliases list; dead after conv1)
  unsigned char* feats = (unsigned char*)(ws + 16555520);  // 77,070,336 (fp8 e4m3)
  float*  partial= (float*) (ws + 16555520);   //   9,633,792 (aliases feats; used after pooling)

  (void)hipMemsetAsync(ws + 16141312, 0, 6272, stream);   // counts+sims+scnt only
  prep_edge_k<<<441, 256, 0, stream>>>(c2w, c2b, bn2g, bn2b, bn2m, bn2v, wt2, bias2,
                                       c1w, c1b, bn1g, bn1b, bn1m, bn1v, wA, bias1,
                                       img, seg, ew, out, counts, sims, scnt);
  conv1_scan_k<<<394, 256, 0, stream>>>(img, wA, bias1, xbf, scnt, offs, curs);
  conv2_scatter_k<<<dim3(392, 7), 256, 0, stream>>>(xbf, wt2, bias2, feats, seg, curs, list);
  pool_k<<<dim3(196, 8, 2), 192, 0, stream>>>(feats, list, offs, meansum_p, maxv_p);
  reduce_pool_k<<<294, 256, 0, stream>>>(meansum_p, maxv_p, counts, cc);
  fusion_mfma_k<<<dim3(6, 4, 8), 256, 0, stream>>>(cc, fwp, partial);
  fuse_ep_k<<<1176, 256, 0, stream>>>(partial, fbp, sims, counts, cent, pw, pb, out);
}